// Round 12
// baseline (1128.384 us; speedup 1.0000x reference)
//
#include <hip/hip_runtime.h>

typedef __attribute__((ext_vector_type(8))) short bf16x8;
typedef __attribute__((ext_vector_type(4))) float f32x4;
typedef __attribute__((ext_vector_type(4))) ushort u16x4;

// HW bf16 convert (RNE), gfx950 v_cvt_pk_bf16_f32: 2 floats -> 1 VGPR (1 op)
__device__ __forceinline__ unsigned f2b2(float lo, float hi) {
    unsigned r;
    asm("v_cvt_pk_bf16_f32 %0, %1, %2" : "=v"(r) : "v"(lo), "v"(hi));
    return r;
}
__device__ __forceinline__ ushort f2b(float v) {
    return (ushort)f2b2(v, v);
}
__device__ __forceinline__ float b2f(ushort b) {
    union { float f; unsigned u; } x; x.u = ((unsigned)b) << 16; return x.f;
}
// pack two f32 -> two f16 (RTZ), one VALU op
__device__ __forceinline__ unsigned pkf16(float a, float b) {
    unsigned r;
    asm("v_cvt_pkrtz_f16_f32 %0, %1, %2" : "=v"(r) : "v"(a), "v"(b));
    return r;
}
__device__ __forceinline__ float h2f(ushort s) {
    union { ushort s; _Float16 h; } x; x.s = s; return (float)x.h;
}

// async global->LDS 16B per lane; LDS dest = wave-uniform base + lane*16
__device__ __forceinline__ void gl_lds16(const void* g, void* l) {
    __builtin_amdgcn_global_load_lds(
        (__attribute__((address_space(1))) void*)(g),
        (__attribute__((address_space(3))) void*)(l), 16, 0, 0);
}

// ---------------- prep kernels ----------------

__global__ void k_split(const float* __restrict__ src, ushort* __restrict__ hi,
                        ushort* __restrict__ lo, int rows, int K, int Kpad) {
    long total = (long)rows * Kpad;
    for (long idx = (long)blockIdx.x * 256 + threadIdx.x; idx < total;
         idx += (long)gridDim.x * 256) {
        int r = (int)(idx / Kpad), c = (int)(idx % Kpad);
        float v = (c < K) ? src[(long)r * K + c] : 0.f;
        ushort h = f2b(v);
        hi[idx] = h;
        if (lo) lo[idx] = f2b(v - b2f(h));
    }
}

// Wc[n][k] = sum_d qkvW[n][d] * fl1W[d][k];  bc[n] = sum_d qkvW[n][d] * fl1b[d]
__global__ void k_wc(const float* __restrict__ qkvW, const float* __restrict__ fl1W,
                     const float* __restrict__ fl1b, float* __restrict__ Wc,
                     float* __restrict__ bc) {
    int idx = blockIdx.x * 256 + threadIdx.x;
    if (idx >= 384 * 1024) return;
    int n = idx >> 10, k = idx & 1023;
    float s = 0.f;
    #pragma unroll 8
    for (int d = 0; d < 128; ++d) s += qkvW[n * 128 + d] * fl1W[d * 1024 + k];
    Wc[idx] = s;
    if (k == 0) {
        float sb = 0.f;
        #pragma unroll 8
        for (int d = 0; d < 128; ++d) sb += qkvW[n * 128 + d] * fl1b[d];
        bc[n] = sb;
    }
}

__global__ void k_sk(const float* __restrict__ fs, const float* __restrict__ fW,
                     const float* __restrict__ fb, float* __restrict__ sk) {
    int m = blockIdx.x * 256 + threadIdx.x;
    if (m >= 12800) return;
    int b = m / 50, i = m % 50;
    float s = fb[i];
    #pragma unroll 4
    for (int c = 0; c < 36; ++c) s += fs[b * 36 + c] * fW[i * 36 + c];
    sk[m] = s;
}

// GRU(10->10): one wave (=one block of 64) per batch element -> 256 CUs covered
__global__ void k_gru(const float* __restrict__ noise, const float* __restrict__ Wih,
                      const float* __restrict__ Whh, const float* __restrict__ bih,
                      const float* __restrict__ bhh, float* __restrict__ aux) {
    int lane = threadIdx.x & 63;
    int b = blockIdx.x;
    if (b >= 256) return;
    float wih[10] = {}, whh[10] = {};
    float bi = 0.f, bh = 0.f;
    if (lane < 30) {
        #pragma unroll
        for (int c = 0; c < 10; ++c) { wih[c] = Wih[lane * 10 + c]; whh[c] = Whh[lane * 10 + c]; }
        bi = bih[lane]; bh = bhh[lane];
    }
    float h = 0.f;
    for (int t = 0; t < 50; ++t) {
        float xr = (lane < 10) ? noise[(b * 50 + t) * 10 + lane] : 0.f;
        float gi = bi, gh = bh;
        #pragma unroll
        for (int c = 0; c < 10; ++c) {
            float xc = __shfl(xr, c, 64);
            float hc = __shfl(h, c, 64);
            gi += wih[c] * xc; gh += whh[c] * hc;
        }
        float siz = __shfl(gi, lane + 10, 64), shz = __shfl(gh, lane + 10, 64);
        float sin_ = __shfl(gi, lane + 20, 64), shn = __shfl(gh, lane + 20, 64);
        float r = 1.f / (1.f + expf(-(gi + gh)));
        float z = 1.f / (1.f + expf(-(siz + shz)));
        float n = tanhf(sin_ + r * shn);
        float hn = (1.f - z) * n + z * h;
        if (lane < 10) { h = hn; aux[(b * 50 + t) * 10 + lane] = tanhf(hn); }
    }
}

__global__ void k_xbuild(const float* __restrict__ input, const float* __restrict__ aux,
                         const float* __restrict__ sk, ushort* __restrict__ xhi,
                         long M) {
    long idx = (long)blockIdx.x * 256 + threadIdx.x;
    if (idx >= M * 288) return;
    int m = (int)(idx / 288), c = (int)(idx % 288);
    float v;
    if (c < 256) v = input[(long)m * 256 + c];
    else if (c < 266) v = aux[m * 10 + (c - 256)];
    else if (c == 266) v = sk[m];
    else v = 0.f;
    xhi[idx] = f2b(v);
}

// ---------------- plain-bf16 MFMA GEMM (R13, verified) ----------------
template <int MODE>
__global__ __launch_bounds__(256, 3) void k_gemm(
    const ushort* __restrict__ Ahi,
    const ushort* __restrict__ Bhi,
    int N, int K,
    float* outF, ushort* outHi,
    const float* __restrict__ bias,
    const float* __restrict__ bng, const float* __restrict__ bnb,
    const float* __restrict__ bnm, const float* __restrict__ bnv,
    const ushort* resHi) {
    __shared__ __align__(16) ushort S[2][128][32];   // Ah, Bh : 16 KB
    int t = threadIdx.x;
    // XCD swizzle (bijective m204)
    int flat = blockIdx.y * gridDim.x + blockIdx.x;
    int nwg = gridDim.x * gridDim.y;
    int q = nwg >> 3, r = nwg & 7;
    int xcd = flat & 7, seq = flat >> 3;
    int wgid = (xcd < r ? xcd * (q + 1) : r * (q + 1) + (xcd - r) * q) + seq;
    int bx = wgid % gridDim.x, by = wgid / gridDim.x;
    int m0 = by * 128, n0 = bx * 128;
    int w = t >> 6, lane = t & 63;
    int wm = w >> 1, wn = w & 1;
    int lo16 = lane & 15, hi4 = lane >> 4;

    const int srow = lane >> 2;
    const int skoff = ((lane & 3) ^ (srow & 3)) * 8;   // elements
    const int slot8 = (hi4 ^ (lo16 & 3)) * 8;

    f32x4 acc[4][4];
    #pragma unroll
    for (int i = 0; i < 4; ++i)
        #pragma unroll
        for (int j = 0; j < 4; ++j) acc[i][j] = f32x4{0.f, 0.f, 0.f, 0.f};

    const int nk = K / 32;
    for (int kt = 0; kt < nk; ++kt) {
        const int kb = kt * 32;
        #pragma unroll
        for (int i = 0; i < 2; ++i) {
            int rg = w * 32 + i * 16;              // wave-uniform row-group base
            long ga = (long)(m0 + rg + srow) * K + kb + skoff;
            long gb = (long)(n0 + rg + srow) * K + kb + skoff;
            gl_lds16(&Ahi[ga], &S[0][rg][0]);
            gl_lds16(&Bhi[gb], &S[1][rg][0]);
        }
        __syncthreads();
        bf16x8 ah[4], bh[4];
        #pragma unroll
        for (int m = 0; m < 4; ++m) {
            int row = wm * 64 + m * 16 + lo16;
            ah[m] = *(const bf16x8*)&S[0][row][slot8];
        }
        #pragma unroll
        for (int n = 0; n < 4; ++n) {
            int col = wn * 64 + n * 16 + lo16;
            bh[n] = *(const bf16x8*)&S[1][col][slot8];
        }
        #pragma unroll
        for (int m = 0; m < 4; ++m)
            #pragma unroll
            for (int n = 0; n < 4; ++n)
                acc[m][n] = __builtin_amdgcn_mfma_f32_16x16x32_bf16(ah[m], bh[n], acc[m][n], 0, 0, 0);
        __syncthreads();
    }

    #pragma unroll
    for (int n = 0; n < 4; ++n) {
        int gn = n0 + wn * 64 + n * 16 + lo16;
        float bv = bias ? bias[gn] : 0.f;
        float sc = 1.f, sh = 0.f;
        if (MODE >= 1) { sc = bng[gn] * rsqrtf(bnv[gn] + 1e-5f); sh = bnb[gn] - bnm[gn] * sc; }
        #pragma unroll
        for (int m = 0; m < 4; ++m)
            #pragma unroll
            for (int r2 = 0; r2 < 4; ++r2) {
                int gm = m0 + wm * 64 + m * 16 + hi4 * 4 + r2;
                long o = (long)gm * N + gn;
                float v = acc[m][n][r2] + bv;
                if (MODE >= 1) v = fmaxf(v * sc + sh, 0.f);
                if (MODE == 2) v += b2f(resHi[o]);
                if (outF) outF[o] = v;
                if (outHi) outHi[o] = f2b(v);
            }
    }
}

// ---------------- pos (fl2): wave-per-row, vectorized bf16 act loads ----------------
__global__ void k_fl2(const ushort* __restrict__ hA,
                      const float* __restrict__ W, const float* __restrict__ bias,
                      float* __restrict__ pos) {
    int w = threadIdx.x >> 6, lane = threadIdx.x & 63;
    int m = blockIdx.x * 4 + w;
    float a0 = 0.f, a1 = 0.f, a2 = 0.f;
    for (int k0 = lane * 4; k0 < 1024; k0 += 256) {
        long o = (long)m * 1024 + k0;
        u16x4 hv = *(const u16x4*)&hA[o];
        f32x4 w0 = *(const f32x4*)&W[k0];
        f32x4 w1 = *(const f32x4*)&W[1024 + k0];
        f32x4 w2 = *(const f32x4*)&W[2048 + k0];
        #pragma unroll
        for (int e = 0; e < 4; ++e) {
            float x = b2f(hv[e]);
            a0 += x * w0[e]; a1 += x * w1[e]; a2 += x * w2[e];
        }
    }
    #pragma unroll
    for (int off = 32; off; off >>= 1) {
        a0 += __shfl_xor(a0, off, 64);
        a1 += __shfl_xor(a1, off, 64);
        a2 += __shfl_xor(a2, off, 64);
    }
    if (lane == 0) {
        pos[m * 3 + 0] = a0 + bias[0];
        pos[m * 3 + 1] = a1 + bias[1];
        pos[m * 3 + 2] = a2 + bias[2];
    }
}

// ---------------- k_attn2 (R17): fused sim MLP + softmax + agg + fl3 ----------------
// R16 still spilled: full acc2[8][2] (64 AGPR) + racc (32) + ~84 VGPR > 170 cap.
// Fix: epilogue never holds more than one bi's sim.
//  1. Park acc2[4..7] (bs=1 sim) -> H1 as f16 (16KB exact; [dword][tid]
//     interleave = conflict-free; same-lane park/reload -> no barrier; f16 sim
//     roundtrip proven harmless in R9).
//  2. Per bs: recompute h1 (64 rows -> R[0,8K)), barrier, rel via racc[4][2]
//     MFMA -> R[8K,24K) (wave-col-private: written & read by same wave -> no
//     barrier, R6-verified same-wave DS ordering), then verbatim tail with
//     cur[4][2]. Peak: 32(cur)+32(racc) acc + ~84 VGPR ~ 148 < 170. No spill.
// LDS (48KB):
//   main loop: R[0,32K) rel/X, H1[32K,48K) h1/HE  (verbatim R11)
//   epilogue:  H1 = parked bs1 sim f16; R[0,8K) h1-bs; R[8K,24K) rel-bs;
//              aggF f32[128] @24576; part f32[2][4][36] @25088.
__global__ __launch_bounds__(256, 3) void k_attn2(
    const float* __restrict__ qkv, const float* __restrict__ posb,
    const ushort* __restrict__ W1b, const ushort* __restrict__ W2b,
    const float* __restrict__ b1, const ushort* __restrict__ pW2b,
    const float* __restrict__ pW1, const float* __restrict__ pb1,
    const float* __restrict__ pb2,
    const float* __restrict__ fl3W, const float* __restrict__ fl3b,
    float* __restrict__ out, long mbase) {
    __shared__ __align__(16) char smem[49152];
    // bijective XCD remap
    int flat = blockIdx.x, nwg = gridDim.x;
    int q = nwg >> 3, r = nwg & 7;
    int xcd = flat & 7, seq = flat >> 3;
    int wgid = (xcd < r ? xcd * (q + 1) : r * (q + 1) + (xcd - r) * q) + seq;
    int bi0 = wgid * 2;                       // chunk-local first bi
    int t = threadIdx.x, w = t >> 6, lane = t & 63;
    int lo16 = lane & 15, hi4 = lane >> 4;
    char* H1 = smem + 32768;

    // ---- phase A: h1[128][64] -> H1 (thread: one row, 32 e) ----
    {
        int rl = t & 127, eh = t >> 7;
        int biL = bi0 + (rl >> 6);
        int j = rl & 63; int jc = j < 50 ? j : 49;
        int bL = biL / 50;
        int kv = bL * 50 + jc;
        float d0 = posb[biL * 3] - posb[kv * 3];
        float d1 = posb[biL * 3 + 1] - posb[kv * 3 + 1];
        float d2 = posb[biL * 3 + 2] - posb[kv * 3 + 2];
        int swm = (rl & 7) << 4;
        #pragma unroll
        for (int e0 = 0; e0 < 32; e0 += 2) {
            int e = eh * 32 + e0;
            float v0 = fmaxf(pb1[e] + pW1[e * 3] * d0 + pW1[e * 3 + 1] * d1
                             + pW1[e * 3 + 2] * d2, 0.f);
            float v1 = fmaxf(pb1[e + 1] + pW1[e * 3 + 3] * d0 + pW1[e * 3 + 4] * d1
                             + pW1[e * 3 + 5] * d2, 0.f);
            *(unsigned*)(H1 + rl * 128 + ((e * 2) ^ swm)) = f2b2(v0, v1);
        }
    }
    __syncthreads();

    // ---- phase B: rel = h1 . pW2^T + pb2 -> R (MFMA) ----
    {
        f32x4 racc[8][2];
        #pragma unroll
        for (int m = 0; m < 8; ++m)
            #pragma unroll
            for (int n = 0; n < 2; ++n) racc[m][n] = f32x4{0.f, 0.f, 0.f, 0.f};
        #pragma unroll
        for (int kt = 0; kt < 2; ++kt) {
            int k0 = kt * 32 + hi4 * 8;
            bf16x8 bv[2];
            #pragma unroll
            for (int n = 0; n < 2; ++n)
                bv[n] = *(const bf16x8*)&pW2b[(w * 32 + n * 16 + lo16) * 64 + k0];
            #pragma unroll
            for (int m = 0; m < 8; ++m) {
                int row = m * 16 + lo16;
                bf16x8 ha = *(const bf16x8*)(H1 + row * 128 + ((k0 * 2) ^ ((lo16 & 7) << 4)));
                #pragma unroll
                for (int n = 0; n < 2; ++n)
                    racc[m][n] = __builtin_amdgcn_mfma_f32_16x16x32_bf16(ha, bv[n], racc[m][n], 0, 0, 0);
            }
        }
        #pragma unroll
        for (int m = 0; m < 8; ++m)
            #pragma unroll
            for (int n = 0; n < 2; ++n) {
                int col = w * 32 + n * 16 + lo16;
                float pb = pb2[col];
                #pragma unroll
                for (int rr = 0; rr < 4; ++rr) {
                    int row = m * 16 + hi4 * 4 + rr;
                    *(ushort*)(smem + row * 256 + ((col * 2) ^ ((row & 15) << 4))) =
                        f2b(racc[m][n][rr] + pb);
                }
            }
    }
    __syncthreads();

    // ---- phase C: X = q_i - k_j + rel, IN-PLACE over R; j>=50 rows zero ----
    #pragma unroll
    for (int cc = 0; cc < 8; ++cc) {
        int c = cc * 256 + t;
        int row = c >> 4, g16 = c & 15;
        int biL = bi0 + (row >> 6);
        int j = row & 63;
        char* addr = smem + row * 256 + ((g16 * 16) ^ ((row & 15) << 4));
        bf16x8 tv;
        if (j < 50) {
            int bL = biL / 50;
            long kq = (long)biL * 384 + g16 * 8;
            long kk = (long)(bL * 50 + j) * 384 + 128 + g16 * 8;
            f32x4 q0 = *(const f32x4*)&qkv[kq];
            f32x4 q1 = *(const f32x4*)&qkv[kq + 4];
            f32x4 k0v = *(const f32x4*)&qkv[kk];
            f32x4 k1v = *(const f32x4*)&qkv[kk + 4];
            bf16x8 rv = *(bf16x8*)addr;
            unsigned* tu = (unsigned*)&tv;
            #pragma unroll
            for (int i = 0; i < 2; ++i)
                tu[i] = f2b2(q0[2 * i] - k0v[2 * i] + b2f((ushort)rv[2 * i]),
                             q0[2 * i + 1] - k0v[2 * i + 1] + b2f((ushort)rv[2 * i + 1]));
            #pragma unroll
            for (int i = 0; i < 2; ++i)
                tu[2 + i] = f2b2(q1[2 * i] - k1v[2 * i] + b2f((ushort)rv[4 + 2 * i]),
                                 q1[2 * i + 1] - k1v[2 * i + 1] + b2f((ushort)rv[4 + 2 * i + 1]));
        } else {
            #pragma unroll
            for (int e = 0; e < 8; ++e) tv[e] = 0;
        }
        *(bf16x8*)addr = tv;
    }
    __syncthreads();

    // ---- e8 main loop (verified k_sim structure): 2 barriers, 64 MFMA/wave ----
    f32x4 acc2[8][2];
    #pragma unroll
    for (int m = 0; m < 8; ++m)
        #pragma unroll
        for (int n = 0; n < 2; ++n) acc2[m][n] = f32x4{0.f, 0.f, 0.f, 0.f};

    for (int e8 = 0; e8 < 8; ++e8) {
        f32x4 acc1[8];
        #pragma unroll
        for (int m = 0; m < 8; ++m) acc1[m] = f32x4{0.f, 0.f, 0.f, 0.f};
        __builtin_amdgcn_s_setprio(1);
        #pragma unroll
        for (int kt = 0; kt < 4; ++kt) {
            int col = e8 * 64 + w * 16 + lo16;
            int k0 = kt * 32 + hi4 * 8;
            bf16x8 bfv = *(const bf16x8*)&W1b[(long)col * 128 + k0];
            #pragma unroll
            for (int m = 0; m < 8; ++m) {
                int row = m * 16 + lo16;
                bf16x8 af = *(const bf16x8*)(smem + row * 256 +
                              ((k0 * 2) ^ ((row & 15) << 4)));
                acc1[m] = __builtin_amdgcn_mfma_f32_16x16x32_bf16(af, bfv, acc1[m], 0, 0, 0);
            }
        }
        __builtin_amdgcn_s_setprio(0);
        __syncthreads();   // prev GEMM2 reads of H1 done (1st iter: h1 dead)
        {
            int ch = w * 16 + lo16;
            float bb = b1[e8 * 64 + ch];
            #pragma unroll
            for (int m = 0; m < 8; ++m) {
                unsigned p01 = f2b2(fmaxf(acc1[m][0] + bb, 0.f), fmaxf(acc1[m][1] + bb, 0.f));
                unsigned p23 = f2b2(fmaxf(acc1[m][2] + bb, 0.f), fmaxf(acc1[m][3] + bb, 0.f));
                int r0 = m * 16 + hi4 * 4;
                *(ushort*)(H1 + (r0 + 0) * 128 + ((ch * 2) ^ (((r0 + 0) & 7) << 4))) = (ushort)p01;
                *(ushort*)(H1 + (r0 + 1) * 128 + ((ch * 2) ^ (((r0 + 1) & 7) << 4))) = (ushort)(p01 >> 16);
                *(ushort*)(H1 + (r0 + 2) * 128 + ((ch * 2) ^ (((r0 + 2) & 7) << 4))) = (ushort)p23;
                *(ushort*)(H1 + (r0 + 3) * 128 + ((ch * 2) ^ (((r0 + 3) & 7) << 4))) = (ushort)(p23 >> 16);
            }
        }
        __syncthreads();
        #pragma unroll
        for (int kt2 = 0; kt2 < 2; ++kt2) {
            int k0 = kt2 * 32 + hi4 * 8;
            bf16x8 af2[8];
            #pragma unroll
            for (int m = 0; m < 8; ++m) {
                int row = m * 16 + lo16;
                af2[m] = *(const bf16x8*)(H1 + row * 128 + ((k0 * 2) ^ ((lo16 & 7) << 4)));
            }
            __builtin_amdgcn_s_setprio(1);
            #pragma unroll
            for (int n = 0; n < 2; ++n) {
                int col = w * 32 + n * 16 + lo16;
                bf16x8 w2 = *(const bf16x8*)&W2b[(long)col * 512 + e8 * 64 + k0];
                #pragma unroll
                for (int m = 0; m < 8; ++m)
                    acc2[m][n] = __builtin_amdgcn_mfma_f32_16x16x32_bf16(af2[m], w2, acc2[m][n], 0, 0, 0);
            }
            __builtin_amdgcn_s_setprio(0);
        }
    }
    __syncthreads();   // last GEMM1 R-reads + GEMM2 H1-reads done

    // ---- park bs=1 sim half as f16 -> H1 ([dword][tid] interleave) ----
    {
        unsigned* P = (unsigned*)H1;
        #pragma unroll
        for (int m = 0; m < 4; ++m)
            #pragma unroll
            for (int n = 0; n < 2; ++n) {
                P[((m * 2 + n) * 2 + 0) * 256 + t] = pkf16(acc2[4 + m][n][0], acc2[4 + m][n][1]);
                P[((m * 2 + n) * 2 + 1) * 256 + t] = pkf16(acc2[4 + m][n][2], acc2[4 + m][n][3]);
            }
    }
    // no barrier: parked data re-read by the same lane only

    float* aggF = (float*)(smem + 24576);   // f32[128], reused per bs (wave-local)
    float* part = (float*)(smem + 25088);   // f32[2][4][36]

    #pragma unroll 1
    for (int bs = 0; bs < 2; ++bs) {
        int biL = bi0 + bs;
        int bL = biL / 50;
        // sim for this bs
        f32x4 cur[4][2];
        if (bs == 0) {
            #pragma unroll
            for (int m = 0; m < 4; ++m)
                #pragma unroll
                for (int n = 0; n < 2; ++n) cur[m][n] = acc2[m][n];
        } else {
            const unsigned* P = (const unsigned*)H1;
            #pragma unroll
            for (int m = 0; m < 4; ++m)
                #pragma unroll
                for (int n = 0; n < 2; ++n) {
                    unsigned u0 = P[((m * 2 + n) * 2 + 0) * 256 + t];
                    unsigned u1 = P[((m * 2 + n) * 2 + 1) * 256 + t];
                    cur[m][n][0] = h2f((ushort)u0);
                    cur[m][n][1] = h2f((ushort)(u0 >> 16));
                    cur[m][n][2] = h2f((ushort)u1);
                    cur[m][n][3] = h2f((ushort)(u1 >> 16));
                }
        }
        // h1 for this bs -> R[0,8192), rows 0..63, 128B pitch
        {
            int rl = t & 63, eq = t >> 6;
            int jc = rl < 50 ? rl : 49;
            int kv = bL * 50 + jc;
            float d0 = posb[biL * 3] - posb[kv * 3];
            float d1 = posb[biL * 3 + 1] - posb[kv * 3 + 1];
            float d2 = posb[biL * 3 + 2] - posb[kv * 3 + 2];
            int swm = (rl & 7) << 4;
            #pragma unroll
            for (int e0 = 0; e0 < 16; e0 += 2) {
                int e = eq * 16 + e0;
                float v0 = fmaxf(pb1[e] + pW1[e * 3] * d0 + pW1[e * 3 + 1] * d1
                                 + pW1[e * 3 + 2] * d2, 0.f);
                float v1 = fmaxf(pb1[e + 1] + pW1[e * 3 + 3] * d0 + pW1[e * 3 + 4] * d1
                                 + pW1[e * 3 + 5] * d2, 0.f);
                *(unsigned*)(smem + rl * 128 + ((e * 2) ^ swm)) = f2b2(v0, v1);
            }
        }
        __syncthreads();   // h1 complete (rel MFMA reads cross-wave rows); also
                           // fences prev-bs rel reads before overwrite below
        // rel for this bs -> R[8192,24576), rows 0..63 (wave-col-private)
        {
            f32x4 racc[4][2];
            #pragma unroll
            for (int m = 0; m < 4; ++m)
                #pragma unroll
                for (int n = 0; n < 2; ++n) racc[m][n] = f32x4{0.f, 0.f, 0.f, 0.f};
            #pragma unroll
            for (int kt = 0; kt < 2; ++kt) {
                int k0 = kt * 32 + hi4 * 8;
                bf16x8 bv[2];
                #pragma unroll
                for (int n = 0; n < 2; ++n)
                    bv[n] = *(const bf16x8*)&pW2b[(w * 32 + n * 16 + lo16) * 64 + k0];
                #pragma unroll
                for (int m = 0; m < 4; ++m) {
                    int row = m * 16 + lo16;
                    bf16x8 ha = *(const bf16x8*)(smem + row * 128 +
                                  ((k0 * 2) ^ ((lo16 & 7) << 4)));
                    #pragma unroll
                    for (int n = 0; n < 2; ++n)
                        racc[m][n] = __builtin_amdgcn_mfma_f32_16x16x32_bf16(ha, bv[n], racc[m][n], 0, 0, 0);
                }
            }
            #pragma unroll
            for (int m = 0; m < 4; ++m)
                #pragma unroll
                for (int n = 0; n < 2; ++n) {
                    int col = w * 32 + n * 16 + lo16;
                    float pb = pb2[col];
                    #pragma unroll
                    for (int rr = 0; rr < 4; ++rr) {
                        int row = m * 16 + hi4 * 4 + rr;
                        *(ushort*)(smem + 8192 + row * 256 +
                                   ((col * 2) ^ ((row & 15) << 4))) =
                            f2b(racc[m][n][rr] + pb);
                    }
                }
        }
        // rel cols wave-private (same wave writes & reads) -> no barrier

        // ---- tail: softmax + agg + fl3 partials (verified pattern) ----
        float outv[2];
        #pragma unroll
        for (int n = 0; n < 2; ++n) {
            float mx = -1e30f;
            #pragma unroll
            for (int m = 0; m < 4; ++m)
                #pragma unroll
                for (int rr = 0; rr < 4; ++rr) {
                    int j = m * 16 + hi4 * 4 + rr;
                    if (j < 50) mx = fmaxf(mx, cur[m][n][rr]);
                }
            mx = fmaxf(mx, __shfl_xor(mx, 16, 64));
            mx = fmaxf(mx, __shfl_xor(mx, 32, 64));
            float e[4][4];
            float sum = 0.f;
            #pragma unroll
            for (int m = 0; m < 4; ++m)
                #pragma unroll
                for (int rr = 0; rr < 4; ++rr) {
                    int j = m * 16 + hi4 * 4 + rr;
                    float ev = (j < 50) ? __expf(cur[m][n][rr] - mx) : 0.f;
                    e[m][rr] = ev; sum += ev;
                }
            sum += __shfl_xor(sum, 16, 64);
            sum += __shfl_xor(sum, 32, 64);
            float inv = 1.f / sum;
            int col = w * 32 + n * 16 + lo16;
            float ag = 0.f;
            #pragma unroll
            for (int m = 0; m < 4; ++m)
                #pragma unroll
                for (int rr = 0; rr < 4; ++rr) {
                    int j = m * 16 + hi4 * 4 + rr;
                    if (j < 50) {
                        float rl = b2f(*(const ushort*)(smem + 8192 + j * 256 +
                                      ((col * 2) ^ ((j & 15) << 4))));
                        float vv = qkv[(long)(bL * 50 + j) * 384 + 256 + col] + rl;
                        ag += e[m][rr] * inv * vv;
                    }
                }
            ag += __shfl_xor(ag, 16, 64);
            ag += __shfl_xor(ag, 32, 64);
            outv[n] = ag;
        }
        if (hi4 == 0) {
            aggF[w * 32 + lo16] = outv[0];
            aggF[w * 32 + 16 + lo16] = outv[1];
        }
        // fl3 partials: wave-local read of OWN aggF slice (same-wave DS order)
        if (lane < 36) {
            const float* wf = &fl3W[lane * 128 + w * 32];
            const float* af = aggF + w * 32;
            float s = 0.f;
            #pragma unroll 8
            for (int d = 0; d < 32; ++d) s += af[d] * wf[d];
            part[bs * 144 + w * 36 + lane] = s;
        }
        __syncthreads();   // bs0: before bs1 overwrites h1/rel; bs1: part ready
    }

    if (t < 36) {
        float s = fl3b[t] + part[t] + part[36 + t] + part[72 + t] + part[108 + t];
        out[(mbase + bi0) * 36 + t] = tanhf(s);
    } else if (t >= 128 && t < 164) {
        int tt = t - 128;
        float s = fl3b[tt] + part[144 + tt] + part[144 + 36 + tt]
                + part[144 + 72 + tt] + part[144 + 108 + tt];
        out[(mbase + bi0 + 1) * 36 + tt] = tanhf(s);
    }
}

// ---------------- launch ----------------
struct Bufs {
    float *sk, *aux, *qkvF, *posb, *WcF, *bc;
    ushort *xh, *actAh, *actBh;
    ushort *l0Wh, *resWh, *Wch, *aW1b, *aW2b, *pW2b;
};

static size_t plan_ws(char* ws, long MCr, Bufs& B) {
    size_t off = 0;
    auto alloc = [&](size_t n) { char* p = ws + off; off += (n + 255) & ~(size_t)255; return p; };
    B.sk    = (float*) alloc(12800L * 4);
    B.aux   = (float*) alloc(128000L * 4);
    B.xh    = (ushort*)alloc((size_t)MCr * 288 * 2);
    B.actAh = (ushort*)alloc((size_t)MCr * 1024 * 2);
    B.actBh = (ushort*)alloc((size_t)MCr * 1024 * 2);
    B.qkvF  = (float*) alloc((size_t)MCr * 384 * 4);
    B.posb  = (float*) alloc((size_t)MCr * 3 * 4);
    B.l0Wh  = (ushort*)alloc(1024L * 288 * 2);
    B.resWh = (ushort*)alloc(6144L * 1024 * 2);
    B.WcF   = (float*) alloc(384L * 1024 * 4);
    B.Wch   = (ushort*)alloc(384L * 1024 * 2);
    B.bc    = (float*) alloc(384L * 4);
    B.aW1b  = (ushort*)alloc(512L * 128 * 2);
    B.aW2b  = (ushort*)alloc(128L * 512 * 2);
    B.pW2b  = (ushort*)alloc(128L * 64 * 2);
    return off;
}

extern "C" void kernel_launch(void* const* d_in, const int* in_sizes, int n_in,
                              void* d_out, int out_size, void* d_ws, size_t ws_size,
                              hipStream_t stream) {
    (void)in_sizes; (void)n_in;
    const float* input  = (const float*)d_in[0];
    const float* fskel  = (const float*)d_in[1];
    const float* noise  = (const float*)d_in[2];
    const float* firstW = (const float*)d_in[3];
    const float* firstB = (const float*)d_in[4];
    const float* gWih   = (const float*)d_in[5];
    const float* gWhh   = (const float*)d_in[6];
    const float* gbih   = (const float*)d_in[7];
    const float* gbhh   = (const float*)d_in[8];
    const float* l0W    = (const float*)d_in[9];
    const float* l0b    = (const float*)d_in[10];
    const float* resW   = (const float*)d_in[11];
    const float* resB   = (const float*)d_in[12];
    const float* bnG    = (const float*)d_in[13];
    const float* bnB    = (const float*)d_in[14];
    const float* bnM    = (const float*)d_in[15];
    const float* bnV    = (const float*)d_in[16];
    const float* fl1W   = (const float*)d_in[17];
    const float* fl1b   = (const float*)d_in[18];
    const float* fl2W   = (const float*)d_in[19];
    const float* fl2b   = (const float*)d_in[20];
    const float* fl3W   = (const float*)d_in[21];
    const float* fl3b   = (const float*)d_in[22];
    const float* qkvW   = (const float*)d_in[23];
    const float* pW1    = (const float*)d_in[24];
    const float* pb1    = (const float*)d_in[25];
    const float* pW2    = (const float*)d_in[26];
    const float* pb2    = (const float*)d_in[27];
    const float* aW1    = (const float*)d_in[28];
    const float* ab1    = (const float*)d_in[29];
    const float* aW2    = (const float*)d_in[30];
    float* out = (float*)d_out;

    char* ws = (char*)d_ws;
    Bufs B;
    long MCr = 12800;
    while (plan_ws(ws, MCr, B) > ws_size) {
        MCr >>= 1;                                 // 6400, 3200, 1600 (all %50==0)
        if (MCr < 1600) {                          // diagnostic: clean zero output
            hipMemsetAsync(d_out, 0, (size_t)out_size * sizeof(float), stream);
            return;
        }
    }
    const int nchunks = (int)(12800 / MCr);

    // one-time prep
    k_split<<<1152, 256, 0, stream>>>(l0W, B.l0Wh, nullptr, 1024, 267, 288);
    k_split<<<8192, 256, 0, stream>>>(resW, B.resWh, nullptr, 6144, 1024, 1024);
    k_wc<<<1536, 256, 0, stream>>>(qkvW, fl1W, fl1b, B.WcF, B.bc);
    k_split<<<1536, 256, 0, stream>>>(B.WcF, B.Wch, nullptr, 384, 1024, 1024);
    k_split<<<256, 256, 0, stream>>>(aW1, B.aW1b, nullptr, 512, 128, 128);
    k_split<<<256, 256, 0, stream>>>(aW2, B.aW2b, nullptr, 128, 512, 512);
    k_split<<<32, 256, 0, stream>>>(pW2, B.pW2b, nullptr, 128, 64, 64);
    k_sk<<<50, 256, 0, stream>>>(fskel, firstW, firstB, B.sk);
    k_gru<<<256, 64, 0, stream>>>(noise, gWih, gWhh, gbih, gbhh, B.aux);

    for (int c = 0; c < nchunks; ++c) {
        long mbase = (long)c * MCr;
        int xb_grid = (int)((MCr * 288 + 255) / 256);
        k_xbuild<<<xb_grid, 256, 0, stream>>>(input + mbase * 256, B.aux + mbase * 10,
                                              B.sk + mbase, B.xh, MCr);
        dim3 gt(8, (unsigned)(MCr / 128));
        k_gemm<0><<<gt, 256, 0, stream>>>(B.xh, B.l0Wh, 1024, 288,
            nullptr, B.actAh, l0b, nullptr, nullptr, nullptr, nullptr, nullptr);
        for (int blk = 0; blk < 3; ++blk) {
            int j0 = blk * 2, j1 = blk * 2 + 1;
            k_gemm<1><<<gt, 256, 0, stream>>>(B.actAh,
                B.resWh + (size_t)j0 * 1024 * 1024,
                1024, 1024, nullptr, B.actBh, resB + j0 * 1024,
                bnG + j0 * 1024, bnB + j0 * 1024, bnM + j0 * 1024, bnV + j0 * 1024,
                nullptr);
            k_gemm<2><<<gt, 256, 0, stream>>>(B.actBh,
                B.resWh + (size_t)j1 * 1024 * 1024,
                1024, 1024, nullptr, B.actAh, resB + j1 * 1024,
                bnG + j1 * 1024, bnB + j1 * 1024, bnM + j1 * 1024, bnV + j1 * 1024,
                B.actAh);
        }
        dim3 gq(3, (unsigned)(MCr / 128));
        k_gemm<0><<<gq, 256, 0, stream>>>(B.actAh, B.Wch, 384, 1024,
            B.qkvF, nullptr, B.bc, nullptr, nullptr, nullptr, nullptr, nullptr);
        k_fl2<<<(int)(MCr / 4), 256, 0, stream>>>(B.actAh, fl2W, fl2b, B.posb);
        k_attn2<<<(int)(MCr / 2), 256, 0, stream>>>(B.qkvF, B.posb, B.aW1b, B.aW2b,
                                                    ab1, B.pW2b, pW1, pb1, pb2,
                                                    fl3W, fl3b, out, mbase);
    }
}

// Round 13
// 1010.400 us; speedup vs baseline: 1.1168x; 1.1168x over previous
//
#include <hip/hip_runtime.h>

typedef __attribute__((ext_vector_type(8))) short bf16x8;
typedef __attribute__((ext_vector_type(4))) float f32x4;
typedef __attribute__((ext_vector_type(4))) ushort u16x4;

// HW bf16 convert (RNE), gfx950 v_cvt_pk_bf16_f32: 2 floats -> 1 VGPR (1 op)
__device__ __forceinline__ unsigned f2b2(float lo, float hi) {
    unsigned r;
    asm("v_cvt_pk_bf16_f32 %0, %1, %2" : "=v"(r) : "v"(lo), "v"(hi));
    return r;
}
__device__ __forceinline__ ushort f2b(float v) {
    return (ushort)f2b2(v, v);
}
__device__ __forceinline__ float b2f(ushort b) {
    union { float f; unsigned u; } x; x.u = ((unsigned)b) << 16; return x.f;
}

// async global->LDS 16B per lane; LDS dest = wave-uniform base + lane*16
__device__ __forceinline__ void gl_lds16(const void* g, void* l) {
    __builtin_amdgcn_global_load_lds(
        (__attribute__((address_space(1))) void*)(g),
        (__attribute__((address_space(3))) void*)(l), 16, 0, 0);
}

// ---------------- prep kernels ----------------

__global__ void k_split(const float* __restrict__ src, ushort* __restrict__ hi,
                        ushort* __restrict__ lo, int rows, int K, int Kpad) {
    long total = (long)rows * Kpad;
    for (long idx = (long)blockIdx.x * 256 + threadIdx.x; idx < total;
         idx += (long)gridDim.x * 256) {
        int r = (int)(idx / Kpad), c = (int)(idx % Kpad);
        float v = (c < K) ? src[(long)r * K + c] : 0.f;
        ushort h = f2b(v);
        hi[idx] = h;
        if (lo) lo[idx] = f2b(v - b2f(h));
    }
}

// Wc[n][k] = sum_d qkvW[n][d] * fl1W[d][k];  bc[n] = sum_d qkvW[n][d] * fl1b[d]
__global__ void k_wc(const float* __restrict__ qkvW, const float* __restrict__ fl1W,
                     const float* __restrict__ fl1b, float* __restrict__ Wc,
                     float* __restrict__ bc) {
    int idx = blockIdx.x * 256 + threadIdx.x;
    if (idx >= 384 * 1024) return;
    int n = idx >> 10, k = idx & 1023;
    float s = 0.f;
    #pragma unroll 8
    for (int d = 0; d < 128; ++d) s += qkvW[n * 128 + d] * fl1W[d * 1024 + k];
    Wc[idx] = s;
    if (k == 0) {
        float sb = 0.f;
        #pragma unroll 8
        for (int d = 0; d < 128; ++d) sb += qkvW[n * 128 + d] * fl1b[d];
        bc[n] = sb;
    }
}

__global__ void k_sk(const float* __restrict__ fs, const float* __restrict__ fW,
                     const float* __restrict__ fb, float* __restrict__ sk) {
    int m = blockIdx.x * 256 + threadIdx.x;
    if (m >= 12800) return;
    int b = m / 50, i = m % 50;
    float s = fb[i];
    #pragma unroll 4
    for (int c = 0; c < 36; ++c) s += fs[b * 36 + c] * fW[i * 36 + c];
    sk[m] = s;
}

// GRU(10->10): one wave (=one block of 64) per batch element -> 256 CUs covered
__global__ void k_gru(const float* __restrict__ noise, const float* __restrict__ Wih,
                      const float* __restrict__ Whh, const float* __restrict__ bih,
                      const float* __restrict__ bhh, float* __restrict__ aux) {
    int lane = threadIdx.x & 63;
    int b = blockIdx.x;
    if (b >= 256) return;
    float wih[10] = {}, whh[10] = {};
    float bi = 0.f, bh = 0.f;
    if (lane < 30) {
        #pragma unroll
        for (int c = 0; c < 10; ++c) { wih[c] = Wih[lane * 10 + c]; whh[c] = Whh[lane * 10 + c]; }
        bi = bih[lane]; bh = bhh[lane];
    }
    float h = 0.f;
    for (int t = 0; t < 50; ++t) {
        float xr = (lane < 10) ? noise[(b * 50 + t) * 10 + lane] : 0.f;
        float gi = bi, gh = bh;
        #pragma unroll
        for (int c = 0; c < 10; ++c) {
            float xc = __shfl(xr, c, 64);
            float hc = __shfl(h, c, 64);
            gi += wih[c] * xc; gh += whh[c] * hc;
        }
        float siz = __shfl(gi, lane + 10, 64), shz = __shfl(gh, lane + 10, 64);
        float sin_ = __shfl(gi, lane + 20, 64), shn = __shfl(gh, lane + 20, 64);
        float r = 1.f / (1.f + expf(-(gi + gh)));
        float z = 1.f / (1.f + expf(-(siz + shz)));
        float n = tanhf(sin_ + r * shn);
        float hn = (1.f - z) * n + z * h;
        if (lane < 10) { h = hn; aux[(b * 50 + t) * 10 + lane] = tanhf(hn); }
    }
}

__global__ void k_xbuild(const float* __restrict__ input, const float* __restrict__ aux,
                         const float* __restrict__ sk, ushort* __restrict__ xhi,
                         long M) {
    long idx = (long)blockIdx.x * 256 + threadIdx.x;
    if (idx >= M * 288) return;
    int m = (int)(idx / 288), c = (int)(idx % 288);
    float v;
    if (c < 256) v = input[(long)m * 256 + c];
    else if (c < 266) v = aux[m * 10 + (c - 256)];
    else if (c == 266) v = sk[m];
    else v = 0.f;
    xhi[idx] = f2b(v);
}

// ---------------- plain-bf16 MFMA GEMM (R13, verified) ----------------
template <int MODE>
__global__ __launch_bounds__(256, 3) void k_gemm(
    const ushort* __restrict__ Ahi,
    const ushort* __restrict__ Bhi,
    int N, int K,
    float* outF, ushort* outHi,
    const float* __restrict__ bias,
    const float* __restrict__ bng, const float* __restrict__ bnb,
    const float* __restrict__ bnm, const float* __restrict__ bnv,
    const ushort* resHi) {
    __shared__ __align__(16) ushort S[2][128][32];   // Ah, Bh : 16 KB
    int t = threadIdx.x;
    // XCD swizzle (bijective m204)
    int flat = blockIdx.y * gridDim.x + blockIdx.x;
    int nwg = gridDim.x * gridDim.y;
    int q = nwg >> 3, r = nwg & 7;
    int xcd = flat & 7, seq = flat >> 3;
    int wgid = (xcd < r ? xcd * (q + 1) : r * (q + 1) + (xcd - r) * q) + seq;
    int bx = wgid % gridDim.x, by = wgid / gridDim.x;
    int m0 = by * 128, n0 = bx * 128;
    int w = t >> 6, lane = t & 63;
    int wm = w >> 1, wn = w & 1;
    int lo16 = lane & 15, hi4 = lane >> 4;

    const int srow = lane >> 2;
    const int skoff = ((lane & 3) ^ (srow & 3)) * 8;   // elements
    const int slot8 = (hi4 ^ (lo16 & 3)) * 8;

    f32x4 acc[4][4];
    #pragma unroll
    for (int i = 0; i < 4; ++i)
        #pragma unroll
        for (int j = 0; j < 4; ++j) acc[i][j] = f32x4{0.f, 0.f, 0.f, 0.f};

    const int nk = K / 32;
    for (int kt = 0; kt < nk; ++kt) {
        const int kb = kt * 32;
        #pragma unroll
        for (int i = 0; i < 2; ++i) {
            int rg = w * 32 + i * 16;              // wave-uniform row-group base
            long ga = (long)(m0 + rg + srow) * K + kb + skoff;
            long gb = (long)(n0 + rg + srow) * K + kb + skoff;
            gl_lds16(&Ahi[ga], &S[0][rg][0]);
            gl_lds16(&Bhi[gb], &S[1][rg][0]);
        }
        __syncthreads();
        bf16x8 ah[4], bh[4];
        #pragma unroll
        for (int m = 0; m < 4; ++m) {
            int row = wm * 64 + m * 16 + lo16;
            ah[m] = *(const bf16x8*)&S[0][row][slot8];
        }
        #pragma unroll
        for (int n = 0; n < 4; ++n) {
            int col = wn * 64 + n * 16 + lo16;
            bh[n] = *(const bf16x8*)&S[1][col][slot8];
        }
        #pragma unroll
        for (int m = 0; m < 4; ++m)
            #pragma unroll
            for (int n = 0; n < 4; ++n)
                acc[m][n] = __builtin_amdgcn_mfma_f32_16x16x32_bf16(ah[m], bh[n], acc[m][n], 0, 0, 0);
        __syncthreads();
    }

    #pragma unroll
    for (int n = 0; n < 4; ++n) {
        int gn = n0 + wn * 64 + n * 16 + lo16;
        float bv = bias ? bias[gn] : 0.f;
        float sc = 1.f, sh = 0.f;
        if (MODE >= 1) { sc = bng[gn] * rsqrtf(bnv[gn] + 1e-5f); sh = bnb[gn] - bnm[gn] * sc; }
        #pragma unroll
        for (int m = 0; m < 4; ++m)
            #pragma unroll
            for (int r2 = 0; r2 < 4; ++r2) {
                int gm = m0 + wm * 64 + m * 16 + hi4 * 4 + r2;
                long o = (long)gm * N + gn;
                float v = acc[m][n][r2] + bv;
                if (MODE >= 1) v = fmaxf(v * sc + sh, 0.f);
                if (MODE == 2) v += b2f(resHi[o]);
                if (outF) outF[o] = v;
                if (outHi) outHi[o] = f2b(v);
            }
    }
}

// ---------------- pos (fl2): wave-per-row, vectorized bf16 act loads ----------------
__global__ void k_fl2(const ushort* __restrict__ hA,
                      const float* __restrict__ W, const float* __restrict__ bias,
                      float* __restrict__ pos) {
    int w = threadIdx.x >> 6, lane = threadIdx.x & 63;
    int m = blockIdx.x * 4 + w;
    float a0 = 0.f, a1 = 0.f, a2 = 0.f;
    for (int k0 = lane * 4; k0 < 1024; k0 += 256) {
        long o = (long)m * 1024 + k0;
        u16x4 hv = *(const u16x4*)&hA[o];
        f32x4 w0 = *(const f32x4*)&W[k0];
        f32x4 w1 = *(const f32x4*)&W[1024 + k0];
        f32x4 w2 = *(const f32x4*)&W[2048 + k0];
        #pragma unroll
        for (int e = 0; e < 4; ++e) {
            float x = b2f(hv[e]);
            a0 += x * w0[e]; a1 += x * w1[e]; a2 += x * w2[e];
        }
    }
    #pragma unroll
    for (int off = 32; off; off >>= 1) {
        a0 += __shfl_xor(a0, off, 64);
        a1 += __shfl_xor(a1, off, 64);
        a2 += __shfl_xor(a2, off, 64);
    }
    if (lane == 0) {
        pos[m * 3 + 0] = a0 + bias[0];
        pos[m * 3 + 1] = a1 + bias[1];
        pos[m * 3 + 2] = a2 + bias[2];
    }
}

// ---------------- k_attn2 (R18): fused sim MLP + softmax + agg + fl3 ----------------
// R10/R11/R12 lesson: under (256,3) (~168-reg cap) this fused kernel ALWAYS
// spills somewhere (main-loop 96 acc regs + epilogue state + ~84 arch VGPRs).
// Fix: give it the registers -- __launch_bounds__(256,2) = 256-reg budget
// (R5 precedent: (256,2) ran 128 accum regs spill-free at VGPR_Count 128).
// Occupancy cost 3->2 blocks measured ~15% (R5); spill was costing ~2x.
// Structure = R11 verbatim (passed): bi-aligned 2-bi block, register sim,
// full-width epilogue recompute (racc[8][2] single pass is fine at 256 regs).
// LDS (48KB):
//   [0,32768)      R: rel -> X (in-place) -> rel (recomputed), [128][256B],
//                  swz byte = row*256 + ((d*2)^((row&15)<<4))
//   [32768,49152)  H1: h1 / HE / h1-recompute, [128][128B], swz (c*2)^((r&7)<<4)
//                  then aggF f32[2][128] @32768, part f32[2][4][36] @33792.
__global__ __launch_bounds__(256, 2) void k_attn2(
    const float* __restrict__ qkv, const float* __restrict__ posb,
    const ushort* __restrict__ W1b, const ushort* __restrict__ W2b,
    const float* __restrict__ b1, const ushort* __restrict__ pW2b,
    const float* __restrict__ pW1, const float* __restrict__ pb1,
    const float* __restrict__ pb2,
    const float* __restrict__ fl3W, const float* __restrict__ fl3b,
    float* __restrict__ out, long mbase) {
    __shared__ __align__(16) char smem[49152];
    // bijective XCD remap
    int flat = blockIdx.x, nwg = gridDim.x;
    int q = nwg >> 3, r = nwg & 7;
    int xcd = flat & 7, seq = flat >> 3;
    int wgid = (xcd < r ? xcd * (q + 1) : r * (q + 1) + (xcd - r) * q) + seq;
    int bi0 = wgid * 2;                       // chunk-local first bi
    int t = threadIdx.x, w = t >> 6, lane = t & 63;
    int lo16 = lane & 15, hi4 = lane >> 4;
    char* H1 = smem + 32768;

    // ---- phase A: h1[128][64] -> H1 (thread: one row, 32 e) ----
    {
        int rl = t & 127, eh = t >> 7;
        int biL = bi0 + (rl >> 6);
        int j = rl & 63; int jc = j < 50 ? j : 49;
        int bL = biL / 50;
        int kv = bL * 50 + jc;
        float d0 = posb[biL * 3] - posb[kv * 3];
        float d1 = posb[biL * 3 + 1] - posb[kv * 3 + 1];
        float d2 = posb[biL * 3 + 2] - posb[kv * 3 + 2];
        int swm = (rl & 7) << 4;
        #pragma unroll
        for (int e0 = 0; e0 < 32; e0 += 2) {
            int e = eh * 32 + e0;
            float v0 = fmaxf(pb1[e] + pW1[e * 3] * d0 + pW1[e * 3 + 1] * d1
                             + pW1[e * 3 + 2] * d2, 0.f);
            float v1 = fmaxf(pb1[e + 1] + pW1[e * 3 + 3] * d0 + pW1[e * 3 + 4] * d1
                             + pW1[e * 3 + 5] * d2, 0.f);
            *(unsigned*)(H1 + rl * 128 + ((e * 2) ^ swm)) = f2b2(v0, v1);
        }
    }
    __syncthreads();

    // ---- phase B: rel = h1 . pW2^T + pb2 -> R (MFMA) ----
    {
        f32x4 racc[8][2];
        #pragma unroll
        for (int m = 0; m < 8; ++m)
            #pragma unroll
            for (int n = 0; n < 2; ++n) racc[m][n] = f32x4{0.f, 0.f, 0.f, 0.f};
        #pragma unroll
        for (int kt = 0; kt < 2; ++kt) {
            int k0 = kt * 32 + hi4 * 8;
            bf16x8 bv[2];
            #pragma unroll
            for (int n = 0; n < 2; ++n)
                bv[n] = *(const bf16x8*)&pW2b[(w * 32 + n * 16 + lo16) * 64 + k0];
            #pragma unroll
            for (int m = 0; m < 8; ++m) {
                int row = m * 16 + lo16;
                bf16x8 ha = *(const bf16x8*)(H1 + row * 128 + ((k0 * 2) ^ ((lo16 & 7) << 4)));
                #pragma unroll
                for (int n = 0; n < 2; ++n)
                    racc[m][n] = __builtin_amdgcn_mfma_f32_16x16x32_bf16(ha, bv[n], racc[m][n], 0, 0, 0);
            }
        }
        #pragma unroll
        for (int m = 0; m < 8; ++m)
            #pragma unroll
            for (int n = 0; n < 2; ++n) {
                int col = w * 32 + n * 16 + lo16;
                float pb = pb2[col];
                #pragma unroll
                for (int rr = 0; rr < 4; ++rr) {
                    int row = m * 16 + hi4 * 4 + rr;
                    *(ushort*)(smem + row * 256 + ((col * 2) ^ ((row & 15) << 4))) =
                        f2b(racc[m][n][rr] + pb);
                }
            }
    }
    __syncthreads();

    // ---- phase C: X = q_i - k_j + rel, IN-PLACE over R; j>=50 rows zero ----
    #pragma unroll
    for (int cc = 0; cc < 8; ++cc) {
        int c = cc * 256 + t;
        int row = c >> 4, g16 = c & 15;
        int biL = bi0 + (row >> 6);
        int j = row & 63;
        char* addr = smem + row * 256 + ((g16 * 16) ^ ((row & 15) << 4));
        bf16x8 tv;
        if (j < 50) {
            int bL = biL / 50;
            long kq = (long)biL * 384 + g16 * 8;
            long kk = (long)(bL * 50 + j) * 384 + 128 + g16 * 8;
            f32x4 q0 = *(const f32x4*)&qkv[kq];
            f32x4 q1 = *(const f32x4*)&qkv[kq + 4];
            f32x4 k0v = *(const f32x4*)&qkv[kk];
            f32x4 k1v = *(const f32x4*)&qkv[kk + 4];
            bf16x8 rv = *(bf16x8*)addr;
            unsigned* tu = (unsigned*)&tv;
            #pragma unroll
            for (int i = 0; i < 2; ++i)
                tu[i] = f2b2(q0[2 * i] - k0v[2 * i] + b2f((ushort)rv[2 * i]),
                             q0[2 * i + 1] - k0v[2 * i + 1] + b2f((ushort)rv[2 * i + 1]));
            #pragma unroll
            for (int i = 0; i < 2; ++i)
                tu[2 + i] = f2b2(q1[2 * i] - k1v[2 * i] + b2f((ushort)rv[4 + 2 * i]),
                                 q1[2 * i + 1] - k1v[2 * i + 1] + b2f((ushort)rv[4 + 2 * i + 1]));
        } else {
            #pragma unroll
            for (int e = 0; e < 8; ++e) tv[e] = 0;
        }
        *(bf16x8*)addr = tv;
    }
    __syncthreads();

    // ---- e8 main loop (verified k_sim structure): 2 barriers, 64 MFMA/wave ----
    f32x4 acc2[8][2];
    #pragma unroll
    for (int m = 0; m < 8; ++m)
        #pragma unroll
        for (int n = 0; n < 2; ++n) acc2[m][n] = f32x4{0.f, 0.f, 0.f, 0.f};

    for (int e8 = 0; e8 < 8; ++e8) {
        f32x4 acc1[8];
        #pragma unroll
        for (int m = 0; m < 8; ++m) acc1[m] = f32x4{0.f, 0.f, 0.f, 0.f};
        __builtin_amdgcn_s_setprio(1);
        #pragma unroll
        for (int kt = 0; kt < 4; ++kt) {
            int col = e8 * 64 + w * 16 + lo16;
            int k0 = kt * 32 + hi4 * 8;
            bf16x8 bfv = *(const bf16x8*)&W1b[(long)col * 128 + k0];
            #pragma unroll
            for (int m = 0; m < 8; ++m) {
                int row = m * 16 + lo16;
                bf16x8 af = *(const bf16x8*)(smem + row * 256 +
                              ((k0 * 2) ^ ((row & 15) << 4)));
                acc1[m] = __builtin_amdgcn_mfma_f32_16x16x32_bf16(af, bfv, acc1[m], 0, 0, 0);
            }
        }
        __builtin_amdgcn_s_setprio(0);
        __syncthreads();   // prev GEMM2 reads of H1 done (1st iter: h1 dead)
        {
            int ch = w * 16 + lo16;
            float bb = b1[e8 * 64 + ch];
            #pragma unroll
            for (int m = 0; m < 8; ++m) {
                unsigned p01 = f2b2(fmaxf(acc1[m][0] + bb, 0.f), fmaxf(acc1[m][1] + bb, 0.f));
                unsigned p23 = f2b2(fmaxf(acc1[m][2] + bb, 0.f), fmaxf(acc1[m][3] + bb, 0.f));
                int r0 = m * 16 + hi4 * 4;
                *(ushort*)(H1 + (r0 + 0) * 128 + ((ch * 2) ^ (((r0 + 0) & 7) << 4))) = (ushort)p01;
                *(ushort*)(H1 + (r0 + 1) * 128 + ((ch * 2) ^ (((r0 + 1) & 7) << 4))) = (ushort)(p01 >> 16);
                *(ushort*)(H1 + (r0 + 2) * 128 + ((ch * 2) ^ (((r0 + 2) & 7) << 4))) = (ushort)p23;
                *(ushort*)(H1 + (r0 + 3) * 128 + ((ch * 2) ^ (((r0 + 3) & 7) << 4))) = (ushort)(p23 >> 16);
            }
        }
        __syncthreads();
        #pragma unroll
        for (int kt2 = 0; kt2 < 2; ++kt2) {
            int k0 = kt2 * 32 + hi4 * 8;
            bf16x8 af2[8];
            #pragma unroll
            for (int m = 0; m < 8; ++m) {
                int row = m * 16 + lo16;
                af2[m] = *(const bf16x8*)(H1 + row * 128 + ((k0 * 2) ^ ((lo16 & 7) << 4)));
            }
            __builtin_amdgcn_s_setprio(1);
            #pragma unroll
            for (int n = 0; n < 2; ++n) {
                int col = w * 32 + n * 16 + lo16;
                bf16x8 w2 = *(const bf16x8*)&W2b[(long)col * 512 + e8 * 64 + k0];
                #pragma unroll
                for (int m = 0; m < 8; ++m)
                    acc2[m][n] = __builtin_amdgcn_mfma_f32_16x16x32_bf16(af2[m], w2, acc2[m][n], 0, 0, 0);
            }
            __builtin_amdgcn_s_setprio(0);
        }
    }
    __syncthreads();   // last GEMM1 R-reads + GEMM2 H1-reads done

    // ---- recompute h1 -> H1 (X dead; H1 dead) ----
    {
        int rl = t & 127, eh = t >> 7;
        int biL = bi0 + (rl >> 6);
        int j = rl & 63; int jc = j < 50 ? j : 49;
        int bL = biL / 50;
        int kv = bL * 50 + jc;
        float d0 = posb[biL * 3] - posb[kv * 3];
        float d1 = posb[biL * 3 + 1] - posb[kv * 3 + 1];
        float d2 = posb[biL * 3 + 2] - posb[kv * 3 + 2];
        int swm = (rl & 7) << 4;
        #pragma unroll
        for (int e0 = 0; e0 < 32; e0 += 2) {
            int e = eh * 32 + e0;
            float v0 = fmaxf(pb1[e] + pW1[e * 3] * d0 + pW1[e * 3 + 1] * d1
                             + pW1[e * 3 + 2] * d2, 0.f);
            float v1 = fmaxf(pb1[e + 1] + pW1[e * 3 + 3] * d0 + pW1[e * 3 + 4] * d1
                             + pW1[e * 3 + 5] * d2, 0.f);
            *(unsigned*)(H1 + rl * 128 + ((e * 2) ^ swm)) = f2b2(v0, v1);
        }
    }
    __syncthreads();

    // ---- recompute rel -> R (phase B repeat; fits at 256-reg budget) ----
    {
        f32x4 racc[8][2];
        #pragma unroll
        for (int m = 0; m < 8; ++m)
            #pragma unroll
            for (int n = 0; n < 2; ++n) racc[m][n] = f32x4{0.f, 0.f, 0.f, 0.f};
        #pragma unroll
        for (int kt = 0; kt < 2; ++kt) {
            int k0 = kt * 32 + hi4 * 8;
            bf16x8 bv[2];
            #pragma unroll
            for (int n = 0; n < 2; ++n)
                bv[n] = *(const bf16x8*)&pW2b[(w * 32 + n * 16 + lo16) * 64 + k0];
            #pragma unroll
            for (int m = 0; m < 8; ++m) {
                int row = m * 16 + lo16;
                bf16x8 ha = *(const bf16x8*)(H1 + row * 128 + ((k0 * 2) ^ ((lo16 & 7) << 4)));
                #pragma unroll
                for (int n = 0; n < 2; ++n)
                    racc[m][n] = __builtin_amdgcn_mfma_f32_16x16x32_bf16(ha, bv[n], racc[m][n], 0, 0, 0);
            }
        }
        #pragma unroll
        for (int m = 0; m < 8; ++m)
            #pragma unroll
            for (int n = 0; n < 2; ++n) {
                int col = w * 32 + n * 16 + lo16;
                float pb = pb2[col];
                #pragma unroll
                for (int rr = 0; rr < 4; ++rr) {
                    int row = m * 16 + hi4 * 4 + rr;
                    *(ushort*)(smem + row * 256 + ((col * 2) ^ ((row & 15) << 4))) =
                        f2b(racc[m][n][rr] + pb);
                }
            }
    }
    __syncthreads();   // rel complete (tail reads rows written by other waves)

    // ---- tail: softmax + agg + fl3, per bi (verified R0 tail, m-offset) ----
    float* aggF = (float*)H1;             // [2][128]
    float* part = (float*)(H1 + 1024);    // [2][4][36] -> bs*144 + w*36 + l
    #pragma unroll
    for (int bs = 0; bs < 2; ++bs) {
        int biL = bi0 + bs;
        int bL = biL / 50;
        float outv[2];
        #pragma unroll
        for (int n = 0; n < 2; ++n) {
            float mx = -1e30f;
            #pragma unroll
            for (int m = 0; m < 4; ++m)
                #pragma unroll
                for (int rr = 0; rr < 4; ++rr) {
                    int j = m * 16 + hi4 * 4 + rr;
                    if (j < 50) mx = fmaxf(mx, acc2[bs * 4 + m][n][rr]);
                }
            mx = fmaxf(mx, __shfl_xor(mx, 16, 64));
            mx = fmaxf(mx, __shfl_xor(mx, 32, 64));
            float e[4][4];
            float sum = 0.f;
            #pragma unroll
            for (int m = 0; m < 4; ++m)
                #pragma unroll
                for (int rr = 0; rr < 4; ++rr) {
                    int j = m * 16 + hi4 * 4 + rr;
                    float ev = (j < 50) ? __expf(acc2[bs * 4 + m][n][rr] - mx) : 0.f;
                    e[m][rr] = ev; sum += ev;
                }
            sum += __shfl_xor(sum, 16, 64);
            sum += __shfl_xor(sum, 32, 64);
            float inv = 1.f / sum;
            int col = w * 32 + n * 16 + lo16;
            float ag = 0.f;
            #pragma unroll
            for (int m = 0; m < 4; ++m)
                #pragma unroll
                for (int rr = 0; rr < 4; ++rr) {
                    int j = m * 16 + hi4 * 4 + rr;
                    if (j < 50) {
                        int row = bs * 64 + j;
                        float rl = b2f(*(const ushort*)(smem + row * 256 +
                                      ((col * 2) ^ ((j & 15) << 4))));
                        float vv = qkv[(long)(bL * 50 + j) * 384 + 256 + col] + rl;
                        ag += e[m][rr] * inv * vv;
                    }
                }
            ag += __shfl_xor(ag, 16, 64);
            ag += __shfl_xor(ag, 32, 64);
            outv[n] = ag;
        }
        if (hi4 == 0) {
            aggF[bs * 128 + w * 32 + lo16] = outv[0];
            aggF[bs * 128 + w * 32 + 16 + lo16] = outv[1];
        }
        // fl3 partials: wave-local read of OWN aggF slice (same-wave DS order)
        if (lane < 36) {
            const float* wf = &fl3W[lane * 128 + w * 32];
            const float* af = aggF + bs * 128 + w * 32;
            float s = 0.f;
            #pragma unroll 8
            for (int d = 0; d < 32; ++d) s += af[d] * wf[d];
            part[bs * 144 + w * 36 + lane] = s;
        }
    }
    __syncthreads();

    if (t < 36) {
        float s = fl3b[t] + part[t] + part[36 + t] + part[72 + t] + part[108 + t];
        out[(mbase + bi0) * 36 + t] = tanhf(s);
    } else if (t >= 128 && t < 164) {
        int tt = t - 128;
        float s = fl3b[tt] + part[144 + tt] + part[144 + 36 + tt]
                + part[144 + 72 + tt] + part[144 + 108 + tt];
        out[(mbase + bi0 + 1) * 36 + tt] = tanhf(s);
    }
}

// ---------------- launch ----------------
struct Bufs {
    float *sk, *aux, *qkvF, *posb, *WcF, *bc;
    ushort *xh, *actAh, *actBh;
    ushort *l0Wh, *resWh, *Wch, *aW1b, *aW2b, *pW2b;
};

static size_t plan_ws(char* ws, long MCr, Bufs& B) {
    size_t off = 0;
    auto alloc = [&](size_t n) { char* p = ws + off; off += (n + 255) & ~(size_t)255; return p; };
    B.sk    = (float*) alloc(12800L * 4);
    B.aux   = (float*) alloc(128000L * 4);
    B.xh    = (ushort*)alloc((size_t)MCr * 288 * 2);
    B.actAh = (ushort*)alloc((size_t)MCr * 1024 * 2);
    B.actBh = (ushort*)alloc((size_t)MCr * 1024 * 2);
    B.qkvF  = (float*) alloc((size_t)MCr * 384 * 4);
    B.posb  = (float*) alloc((size_t)MCr * 3 * 4);
    B.l0Wh  = (ushort*)alloc(1024L * 288 * 2);
    B.resWh = (ushort*)alloc(6144L * 1024 * 2);
    B.WcF   = (float*) alloc(384L * 1024 * 4);
    B.Wch   = (ushort*)alloc(384L * 1024 * 2);
    B.bc    = (float*) alloc(384L * 4);
    B.aW1b  = (ushort*)alloc(512L * 128 * 2);
    B.aW2b  = (ushort*)alloc(128L * 512 * 2);
    B.pW2b  = (ushort*)alloc(128L * 64 * 2);
    return off;
}

extern "C" void kernel_launch(void* const* d_in, const int* in_sizes, int n_in,
                              void* d_out, int out_size, void* d_ws, size_t ws_size,
                              hipStream_t stream) {
    (void)in_sizes; (void)n_in;
    const float* input  = (const float*)d_in[0];
    const float* fskel  = (const float*)d_in[1];
    const float* noise  = (const float*)d_in[2];
    const float* firstW = (const float*)d_in[3];
    const float* firstB = (const float*)d_in[4];
    const float* gWih   = (const float*)d_in[5];
    const float* gWhh   = (const float*)d_in[6];
    const float* gbih   = (const float*)d_in[7];
    const float* gbhh   = (const float*)d_in[8];
    const float* l0W    = (const float*)d_in[9];
    const float* l0b    = (const float*)d_in[10];
    const float* resW   = (const float*)d_in[11];
    const float* resB   = (const float*)d_in[12];
    const float* bnG    = (const float*)d_in[13];
    const float* bnB    = (const float*)d_in[14];
    const float* bnM    = (const float*)d_in[15];
    const float* bnV    = (const float*)d_in[16];
    const float* fl1W   = (const float*)d_in[17];
    const float* fl1b   = (const float*)d_in[18];
    const float* fl2W   = (const float*)d_in[19];
    const float* fl2b   = (const float*)d_in[20];
    const float* fl3W   = (const float*)d_in[21];
    const float* fl3b   = (const float*)d_in[22];
    const float* qkvW   = (const float*)d_in[23];
    const float* pW1    = (const float*)d_in[24];
    const float* pb1    = (const float*)d_in[25];
    const float* pW2    = (const float*)d_in[26];
    const float* pb2    = (const float*)d_in[27];
    const float* aW1    = (const float*)d_in[28];
    const float* ab1    = (const float*)d_in[29];
    const float* aW2    = (const float*)d_in[30];
    float* out = (float*)d_out;

    char* ws = (char*)d_ws;
    Bufs B;
    long MCr = 12800;
    while (plan_ws(ws, MCr, B) > ws_size) {
        MCr >>= 1;                                 // 6400, 3200, 1600 (all %50==0)
        if (MCr < 1600) {                          // diagnostic: clean zero output
            hipMemsetAsync(d_out, 0, (size_t)out_size * sizeof(float), stream);
            return;
        }
    }
    const int nchunks = (int)(12800 / MCr);

    // one-time prep
    k_split<<<1152, 256, 0, stream>>>(l0W, B.l0Wh, nullptr, 1024, 267, 288);
    k_split<<<8192, 256, 0, stream>>>(resW, B.resWh, nullptr, 6144, 1024, 1024);
    k_wc<<<1536, 256, 0, stream>>>(qkvW, fl1W, fl1b, B.WcF, B.bc);
    k_split<<<1536, 256, 0, stream>>>(B.WcF, B.Wch, nullptr, 384, 1024, 1024);
    k_split<<<256, 256, 0, stream>>>(aW1, B.aW1b, nullptr, 512, 128, 128);
    k_split<<<256, 256, 0, stream>>>(aW2, B.aW2b, nullptr, 128, 512, 512);
    k_split<<<32, 256, 0, stream>>>(pW2, B.pW2b, nullptr, 128, 64, 64);
    k_sk<<<50, 256, 0, stream>>>(fskel, firstW, firstB, B.sk);
    k_gru<<<256, 64, 0, stream>>>(noise, gWih, gWhh, gbih, gbhh, B.aux);

    for (int c = 0; c < nchunks; ++c) {
        long mbase = (long)c * MCr;
        int xb_grid = (int)((MCr * 288 + 255) / 256);
        k_xbuild<<<xb_grid, 256, 0, stream>>>(input + mbase * 256, B.aux + mbase * 10,
                                              B.sk + mbase, B.xh, MCr);
        dim3 gt(8, (unsigned)(MCr / 128));
        k_gemm<0><<<gt, 256, 0, stream>>>(B.xh, B.l0Wh, 1024, 288,
            nullptr, B.actAh, l0b, nullptr, nullptr, nullptr, nullptr, nullptr);
        for (int blk = 0; blk < 3; ++blk) {
            int j0 = blk * 2, j1 = blk * 2 + 1;
            k_gemm<1><<<gt, 256, 0, stream>>>(B.actAh,
                B.resWh + (size_t)j0 * 1024 * 1024,
                1024, 1024, nullptr, B.actBh, resB + j0 * 1024,
                bnG + j0 * 1024, bnB + j0 * 1024, bnM + j0 * 1024, bnV + j0 * 1024,
                nullptr);
            k_gemm<2><<<gt, 256, 0, stream>>>(B.actBh,
                B.resWh + (size_t)j1 * 1024 * 1024,
                1024, 1024, nullptr, B.actAh, resB + j1 * 1024,
                bnG + j1 * 1024, bnB + j1 * 1024, bnM + j1 * 1024, bnV + j1 * 1024,
                B.actAh);
        }
        dim3 gq(3, (unsigned)(MCr / 128));
        k_gemm<0><<<gq, 256, 0, stream>>>(B.actAh, B.Wch, 384, 1024,
            B.qkvF, nullptr, B.bc, nullptr, nullptr, nullptr, nullptr, nullptr);
        k_fl2<<<(int)(MCr / 4), 256, 0, stream>>>(B.actAh, fl2W, fl2b, B.posb);
        k_attn2<<<(int)(MCr / 2), 256, 0, stream>>>(B.qkvF, B.posb, B.aW1b, B.aW2b,
                                                    ab1, B.pW2b, pW1, pb1, pb2,
                                                    fl3W, fl3b, out, mbase);
    }
}

// Round 14
// 940.096 us; speedup vs baseline: 1.2003x; 1.0748x over previous
//
#include <hip/hip_runtime.h>

typedef __attribute__((ext_vector_type(8))) short bf16x8;
typedef __attribute__((ext_vector_type(4))) float f32x4;
typedef __attribute__((ext_vector_type(4))) ushort u16x4;

// HW bf16 convert (RNE), gfx950 v_cvt_pk_bf16_f32: 2 floats -> 1 VGPR (1 op)
__device__ __forceinline__ unsigned f2b2(float lo, float hi) {
    unsigned r;
    asm("v_cvt_pk_bf16_f32 %0, %1, %2" : "=v"(r) : "v"(lo), "v"(hi));
    return r;
}
__device__ __forceinline__ ushort f2b(float v) {
    return (ushort)f2b2(v, v);
}
__device__ __forceinline__ float b2f(ushort b) {
    union { float f; unsigned u; } x; x.u = ((unsigned)b) << 16; return x.f;
}

// async global->LDS 16B per lane; LDS dest = wave-uniform base + lane*16
__device__ __forceinline__ void gl_lds16(const void* g, void* l) {
    __builtin_amdgcn_global_load_lds(
        (__attribute__((address_space(1))) void*)(g),
        (__attribute__((address_space(3))) void*)(l), 16, 0, 0);
}

// ---------------- prep kernels ----------------

__global__ void k_split(const float* __restrict__ src, ushort* __restrict__ hi,
                        ushort* __restrict__ lo, int rows, int K, int Kpad) {
    long total = (long)rows * Kpad;
    for (long idx = (long)blockIdx.x * 256 + threadIdx.x; idx < total;
         idx += (long)gridDim.x * 256) {
        int r = (int)(idx / Kpad), c = (int)(idx % Kpad);
        float v = (c < K) ? src[(long)r * K + c] : 0.f;
        ushort h = f2b(v);
        hi[idx] = h;
        if (lo) lo[idx] = f2b(v - b2f(h));
    }
}

// Wc[n][k] = sum_d qkvW[n][d] * fl1W[d][k];  bc[n] = sum_d qkvW[n][d] * fl1b[d]
__global__ void k_wc(const float* __restrict__ qkvW, const float* __restrict__ fl1W,
                     const float* __restrict__ fl1b, float* __restrict__ Wc,
                     float* __restrict__ bc) {
    int idx = blockIdx.x * 256 + threadIdx.x;
    if (idx >= 384 * 1024) return;
    int n = idx >> 10, k = idx & 1023;
    float s = 0.f;
    #pragma unroll 8
    for (int d = 0; d < 128; ++d) s += qkvW[n * 128 + d] * fl1W[d * 1024 + k];
    Wc[idx] = s;
    if (k == 0) {
        float sb = 0.f;
        #pragma unroll 8
        for (int d = 0; d < 128; ++d) sb += qkvW[n * 128 + d] * fl1b[d];
        bc[n] = sb;
    }
}

__global__ void k_sk(const float* __restrict__ fs, const float* __restrict__ fW,
                     const float* __restrict__ fb, float* __restrict__ sk) {
    int m = blockIdx.x * 256 + threadIdx.x;
    if (m >= 12800) return;
    int b = m / 50, i = m % 50;
    float s = fb[i];
    #pragma unroll 4
    for (int c = 0; c < 36; ++c) s += fs[b * 36 + c] * fW[i * 36 + c];
    sk[m] = s;
}

// GRU(10->10): one wave (=one block of 64) per batch element -> 256 CUs covered
__global__ void k_gru(const float* __restrict__ noise, const float* __restrict__ Wih,
                      const float* __restrict__ Whh, const float* __restrict__ bih,
                      const float* __restrict__ bhh, float* __restrict__ aux) {
    int lane = threadIdx.x & 63;
    int b = blockIdx.x;
    if (b >= 256) return;
    float wih[10] = {}, whh[10] = {};
    float bi = 0.f, bh = 0.f;
    if (lane < 30) {
        #pragma unroll
        for (int c = 0; c < 10; ++c) { wih[c] = Wih[lane * 10 + c]; whh[c] = Whh[lane * 10 + c]; }
        bi = bih[lane]; bh = bhh[lane];
    }
    float h = 0.f;
    for (int t = 0; t < 50; ++t) {
        float xr = (lane < 10) ? noise[(b * 50 + t) * 10 + lane] : 0.f;
        float gi = bi, gh = bh;
        #pragma unroll
        for (int c = 0; c < 10; ++c) {
            float xc = __shfl(xr, c, 64);
            float hc = __shfl(h, c, 64);
            gi += wih[c] * xc; gh += whh[c] * hc;
        }
        float siz = __shfl(gi, lane + 10, 64), shz = __shfl(gh, lane + 10, 64);
        float sin_ = __shfl(gi, lane + 20, 64), shn = __shfl(gh, lane + 20, 64);
        float r = 1.f / (1.f + expf(-(gi + gh)));
        float z = 1.f / (1.f + expf(-(siz + shz)));
        float n = tanhf(sin_ + r * shn);
        float hn = (1.f - z) * n + z * h;
        if (lane < 10) { h = hn; aux[(b * 50 + t) * 10 + lane] = tanhf(hn); }
    }
}

__global__ void k_xbuild(const float* __restrict__ input, const float* __restrict__ aux,
                         const float* __restrict__ sk, ushort* __restrict__ xhi,
                         long M) {
    long idx = (long)blockIdx.x * 256 + threadIdx.x;
    if (idx >= M * 288) return;
    int m = (int)(idx / 288), c = (int)(idx % 288);
    float v;
    if (c < 256) v = input[(long)m * 256 + c];
    else if (c < 266) v = aux[m * 10 + (c - 256)];
    else if (c == 266) v = sk[m];
    else v = 0.f;
    xhi[idx] = f2b(v);
}

// ---------------- plain-bf16 MFMA GEMM (R13, verified) ----------------
template <int MODE>
__global__ __launch_bounds__(256, 3) void k_gemm(
    const ushort* __restrict__ Ahi,
    const ushort* __restrict__ Bhi,
    int N, int K,
    float* outF, ushort* outHi,
    const float* __restrict__ bias,
    const float* __restrict__ bng, const float* __restrict__ bnb,
    const float* __restrict__ bnm, const float* __restrict__ bnv,
    const ushort* resHi) {
    __shared__ __align__(16) ushort S[2][128][32];   // Ah, Bh : 16 KB
    int t = threadIdx.x;
    // XCD swizzle (bijective m204)
    int flat = blockIdx.y * gridDim.x + blockIdx.x;
    int nwg = gridDim.x * gridDim.y;
    int q = nwg >> 3, r = nwg & 7;
    int xcd = flat & 7, seq = flat >> 3;
    int wgid = (xcd < r ? xcd * (q + 1) : r * (q + 1) + (xcd - r) * q) + seq;
    int bx = wgid % gridDim.x, by = wgid / gridDim.x;
    int m0 = by * 128, n0 = bx * 128;
    int w = t >> 6, lane = t & 63;
    int wm = w >> 1, wn = w & 1;
    int lo16 = lane & 15, hi4 = lane >> 4;

    const int srow = lane >> 2;
    const int skoff = ((lane & 3) ^ (srow & 3)) * 8;   // elements
    const int slot8 = (hi4 ^ (lo16 & 3)) * 8;

    f32x4 acc[4][4];
    #pragma unroll
    for (int i = 0; i < 4; ++i)
        #pragma unroll
        for (int j = 0; j < 4; ++j) acc[i][j] = f32x4{0.f, 0.f, 0.f, 0.f};

    const int nk = K / 32;
    for (int kt = 0; kt < nk; ++kt) {
        const int kb = kt * 32;
        #pragma unroll
        for (int i = 0; i < 2; ++i) {
            int rg = w * 32 + i * 16;              // wave-uniform row-group base
            long ga = (long)(m0 + rg + srow) * K + kb + skoff;
            long gb = (long)(n0 + rg + srow) * K + kb + skoff;
            gl_lds16(&Ahi[ga], &S[0][rg][0]);
            gl_lds16(&Bhi[gb], &S[1][rg][0]);
        }
        __syncthreads();
        bf16x8 ah[4], bh[4];
        #pragma unroll
        for (int m = 0; m < 4; ++m) {
            int row = wm * 64 + m * 16 + lo16;
            ah[m] = *(const bf16x8*)&S[0][row][slot8];
        }
        #pragma unroll
        for (int n = 0; n < 4; ++n) {
            int col = wn * 64 + n * 16 + lo16;
            bh[n] = *(const bf16x8*)&S[1][col][slot8];
        }
        #pragma unroll
        for (int m = 0; m < 4; ++m)
            #pragma unroll
            for (int n = 0; n < 4; ++n)
                acc[m][n] = __builtin_amdgcn_mfma_f32_16x16x32_bf16(ah[m], bh[n], acc[m][n], 0, 0, 0);
        __syncthreads();
    }

    #pragma unroll
    for (int n = 0; n < 4; ++n) {
        int gn = n0 + wn * 64 + n * 16 + lo16;
        float bv = bias ? bias[gn] : 0.f;
        float sc = 1.f, sh = 0.f;
        if (MODE >= 1) { sc = bng[gn] * rsqrtf(bnv[gn] + 1e-5f); sh = bnb[gn] - bnm[gn] * sc; }
        #pragma unroll
        for (int m = 0; m < 4; ++m)
            #pragma unroll
            for (int r2 = 0; r2 < 4; ++r2) {
                int gm = m0 + wm * 64 + m * 16 + hi4 * 4 + r2;
                long o = (long)gm * N + gn;
                float v = acc[m][n][r2] + bv;
                if (MODE >= 1) v = fmaxf(v * sc + sh, 0.f);
                if (MODE == 2) v += b2f(resHi[o]);
                if (outF) outF[o] = v;
                if (outHi) outHi[o] = f2b(v);
            }
    }
}

// ---------------- pos (fl2): wave-per-row, vectorized bf16 act loads ----------------
__global__ void k_fl2(const ushort* __restrict__ hA,
                      const float* __restrict__ W, const float* __restrict__ bias,
                      float* __restrict__ pos) {
    int w = threadIdx.x >> 6, lane = threadIdx.x & 63;
    int m = blockIdx.x * 4 + w;
    float a0 = 0.f, a1 = 0.f, a2 = 0.f;
    for (int k0 = lane * 4; k0 < 1024; k0 += 256) {
        long o = (long)m * 1024 + k0;
        u16x4 hv = *(const u16x4*)&hA[o];
        f32x4 w0 = *(const f32x4*)&W[k0];
        f32x4 w1 = *(const f32x4*)&W[1024 + k0];
        f32x4 w2 = *(const f32x4*)&W[2048 + k0];
        #pragma unroll
        for (int e = 0; e < 4; ++e) {
            float x = b2f(hv[e]);
            a0 += x * w0[e]; a1 += x * w1[e]; a2 += x * w2[e];
        }
    }
    #pragma unroll
    for (int off = 32; off; off >>= 1) {
        a0 += __shfl_xor(a0, off, 64);
        a1 += __shfl_xor(a1, off, 64);
        a2 += __shfl_xor(a2, off, 64);
    }
    if (lane == 0) {
        pos[m * 3 + 0] = a0 + bias[0];
        pos[m * 3 + 1] = a1 + bias[1];
        pos[m * 3 + 2] = a2 + bias[2];
    }
}

// ---------------- k_sim (R14): batched sim MLP over 640k (i,j) rows ----------------
// Row = bi*50 + j (bi = b*50+i). 128 FULLY-VALID rows per block (no 50/64 waste;
// k_attn's old main loop had 22% padded rows and only 16 MFMA/barrier-half).
// Per block: h1[128][64] (VALU) -> rel via MFMA (h1 x pW2^T, phase0b pattern) ->
// X built IN-PLACE over rel in LDS -> e8 loop {GEMM1 8 m-frags/wave, HE LDS,
// GEMM2 partial} -> sim f16 out. 2x MFMA per barrier vs old k_attn.
// LDS (48KB -> 3 blocks/CU):
//   [0,32768)      R: rel then X, [128 rows][256B pitch], swz (d*2)^((row&15)<<4)
//   [32768,49152)  H1 then HE: [128 rows][128B pitch], swz (c*2)^((row&7)<<4)
__global__ __launch_bounds__(256, 3) void k_sim(
    const float* __restrict__ qkv, const float* __restrict__ posb,
    const ushort* __restrict__ W1b, const ushort* __restrict__ W2b,
    const float* __restrict__ b1, const ushort* __restrict__ pW2b,
    const float* __restrict__ pW1, const float* __restrict__ pb1,
    const float* __restrict__ pb2, _Float16* __restrict__ sim) {
    __shared__ __align__(16) char smem[49152];
    // bijective XCD remap
    int flat = blockIdx.x;
    int nwg = gridDim.x;
    int q = nwg >> 3, r = nwg & 7;
    int xcd = flat & 7, seq = flat >> 3;
    int wgid = (xcd < r ? xcd * (q + 1) : r * (q + 1) + (xcd - r) * q) + seq;
    int R0 = wgid * 128;                      // chunk-local row base
    int t = threadIdx.x, w = t >> 6, lane = t & 63;
    int lo16 = lane & 15, hi4 = lane >> 4;
    char* H1 = smem + 32768;

    // ---- phase A: h1[128][64] -> H1 (each thread: one row-half of 32 e) ----
    {
        int rl = t & 127, eh = t >> 7;
        int g = R0 + rl;
        int bi = g / 50, j = g - bi * 50;
        int b = bi / 50;
        int kv = b * 50 + j;
        float d0 = posb[bi * 3] - posb[kv * 3];
        float d1 = posb[bi * 3 + 1] - posb[kv * 3 + 1];
        float d2 = posb[bi * 3 + 2] - posb[kv * 3 + 2];
        int swm = (rl & 7) << 4;
        #pragma unroll
        for (int e0 = 0; e0 < 32; e0 += 2) {
            int e = eh * 32 + e0;
            float v0 = fmaxf(pb1[e] + pW1[e * 3] * d0 + pW1[e * 3 + 1] * d1
                             + pW1[e * 3 + 2] * d2, 0.f);
            float v1 = fmaxf(pb1[e + 1] + pW1[e * 3 + 3] * d0 + pW1[e * 3 + 4] * d1
                             + pW1[e * 3 + 5] * d2, 0.f);
            *(unsigned*)(H1 + rl * 128 + ((e * 2) ^ swm)) = f2b2(v0, v1);
        }
    }
    __syncthreads();

    // ---- phase B: rel = h1 . pW2^T + pb2 -> R (MFMA, 32/wave) ----
    {
        f32x4 racc[8][2];
        #pragma unroll
        for (int m = 0; m < 8; ++m)
            #pragma unroll
            for (int n = 0; n < 2; ++n) racc[m][n] = f32x4{0.f, 0.f, 0.f, 0.f};
        #pragma unroll
        for (int kt = 0; kt < 2; ++kt) {
            int k0 = kt * 32 + hi4 * 8;
            bf16x8 bv[2];
            #pragma unroll
            for (int n = 0; n < 2; ++n)
                bv[n] = *(const bf16x8*)&pW2b[(w * 32 + n * 16 + lo16) * 64 + k0];
            #pragma unroll
            for (int m = 0; m < 8; ++m) {
                int row = m * 16 + lo16;
                bf16x8 ha = *(const bf16x8*)(H1 + row * 128 + ((k0 * 2) ^ ((lo16 & 7) << 4)));
                #pragma unroll
                for (int n = 0; n < 2; ++n)
                    racc[m][n] = __builtin_amdgcn_mfma_f32_16x16x32_bf16(ha, bv[n], racc[m][n], 0, 0, 0);
            }
        }
        #pragma unroll
        for (int m = 0; m < 8; ++m)
            #pragma unroll
            for (int n = 0; n < 2; ++n) {
                int col = w * 32 + n * 16 + lo16;
                float pb = pb2[col];
                #pragma unroll
                for (int rr = 0; rr < 4; ++rr) {
                    int row = m * 16 + hi4 * 4 + rr;
                    *(ushort*)(smem + row * 256 + ((col * 2) ^ ((row & 15) << 4))) =
                        f2b(racc[m][n][rr] + pb);
                }
            }
    }
    __syncthreads();

    // ---- phase C: X = q_i - k_j + rel, IN-PLACE over R ----
    #pragma unroll
    for (int cc = 0; cc < 8; ++cc) {
        int c = cc * 256 + t;
        int row = c >> 4, g16 = c & 15;
        int g = R0 + row;
        int bi = g / 50, j = g - bi * 50;
        int b = bi / 50;
        long kq = (long)bi * 384 + g16 * 8;
        long kk = (long)(b * 50 + j) * 384 + 128 + g16 * 8;
        f32x4 q0 = *(const f32x4*)&qkv[kq];
        f32x4 q1 = *(const f32x4*)&qkv[kq + 4];
        f32x4 k0v = *(const f32x4*)&qkv[kk];
        f32x4 k1v = *(const f32x4*)&qkv[kk + 4];
        char* addr = smem + row * 256 + ((g16 * 16) ^ ((row & 15) << 4));
        bf16x8 rv = *(bf16x8*)addr;
        bf16x8 tv;
        unsigned* tu = (unsigned*)&tv;
        #pragma unroll
        for (int i = 0; i < 2; ++i)
            tu[i] = f2b2(q0[2 * i] - k0v[2 * i] + b2f((ushort)rv[2 * i]),
                         q0[2 * i + 1] - k0v[2 * i + 1] + b2f((ushort)rv[2 * i + 1]));
        #pragma unroll
        for (int i = 0; i < 2; ++i)
            tu[2 + i] = f2b2(q1[2 * i] - k1v[2 * i] + b2f((ushort)rv[4 + 2 * i]),
                             q1[2 * i + 1] - k1v[2 * i + 1] + b2f((ushort)rv[4 + 2 * i + 1]));
        *(bf16x8*)addr = tv;
    }
    __syncthreads();

    // ---- e8 main loop: 2 barriers per e8, 64 MFMA/wave per e8 ----
    f32x4 acc2[8][2];
    #pragma unroll
    for (int m = 0; m < 8; ++m)
        #pragma unroll
        for (int n = 0; n < 2; ++n) acc2[m][n] = f32x4{0.f, 0.f, 0.f, 0.f};

    for (int e8 = 0; e8 < 8; ++e8) {
        // GEMM1: H[:, wave's 16 cols of e8], K=128, 8 m-frags (bv reused 8x)
        f32x4 acc1[8];
        #pragma unroll
        for (int m = 0; m < 8; ++m) acc1[m] = f32x4{0.f, 0.f, 0.f, 0.f};
        __builtin_amdgcn_s_setprio(1);
        #pragma unroll
        for (int kt = 0; kt < 4; ++kt) {
            int col = e8 * 64 + w * 16 + lo16;
            int k0 = kt * 32 + hi4 * 8;
            bf16x8 bfv = *(const bf16x8*)&W1b[(long)col * 128 + k0];
            #pragma unroll
            for (int m = 0; m < 8; ++m) {
                int row = m * 16 + lo16;
                bf16x8 af = *(const bf16x8*)(smem + row * 256 +
                              ((k0 * 2) ^ ((row & 15) << 4)));
                acc1[m] = __builtin_amdgcn_mfma_f32_16x16x32_bf16(af, bfv, acc1[m], 0, 0, 0);
            }
        }
        __builtin_amdgcn_s_setprio(0);
        __syncthreads();   // prev GEMM2 reads of HE done (1st iter: H1 dead)
        {
            int ch = w * 16 + lo16;
            float bb = b1[e8 * 64 + ch];
            #pragma unroll
            for (int m = 0; m < 8; ++m) {
                unsigned p01 = f2b2(fmaxf(acc1[m][0] + bb, 0.f), fmaxf(acc1[m][1] + bb, 0.f));
                unsigned p23 = f2b2(fmaxf(acc1[m][2] + bb, 0.f), fmaxf(acc1[m][3] + bb, 0.f));
                int r0 = m * 16 + hi4 * 4;
                *(ushort*)(H1 + (r0 + 0) * 128 + ((ch * 2) ^ (((r0 + 0) & 7) << 4))) = (ushort)p01;
                *(ushort*)(H1 + (r0 + 1) * 128 + ((ch * 2) ^ (((r0 + 1) & 7) << 4))) = (ushort)(p01 >> 16);
                *(ushort*)(H1 + (r0 + 2) * 128 + ((ch * 2) ^ (((r0 + 2) & 7) << 4))) = (ushort)p23;
                *(ushort*)(H1 + (r0 + 3) * 128 + ((ch * 2) ^ (((r0 + 3) & 7) << 4))) = (ushort)(p23 >> 16);
            }
        }
        __syncthreads();
        // GEMM2 partial: K chunk [e8*64, e8*64+64)
        #pragma unroll
        for (int kt2 = 0; kt2 < 2; ++kt2) {
            int k0 = kt2 * 32 + hi4 * 8;
            bf16x8 af2[8];
            #pragma unroll
            for (int m = 0; m < 8; ++m) {
                int row = m * 16 + lo16;
                af2[m] = *(const bf16x8*)(H1 + row * 128 + ((k0 * 2) ^ ((lo16 & 7) << 4)));
            }
            __builtin_amdgcn_s_setprio(1);
            #pragma unroll
            for (int n = 0; n < 2; ++n) {
                int col = w * 32 + n * 16 + lo16;
                bf16x8 w2 = *(const bf16x8*)&W2b[(long)col * 512 + e8 * 64 + k0];
                #pragma unroll
                for (int m = 0; m < 8; ++m)
                    acc2[m][n] = __builtin_amdgcn_mfma_f32_16x16x32_bf16(af2[m], w2, acc2[m][n], 0, 0, 0);
            }
            __builtin_amdgcn_s_setprio(0);
        }
    }

    // ---- epilogue: sim (f16) ----
    #pragma unroll
    for (int m = 0; m < 8; ++m)
        #pragma unroll
        for (int n = 0; n < 2; ++n) {
            int col = w * 32 + n * 16 + lo16;
            #pragma unroll
            for (int rr = 0; rr < 4; ++rr) {
                int row = m * 16 + hi4 * 4 + rr;
                sim[(long)(R0 + row) * 128 + col] = (_Float16)acc2[m][n][rr];
            }
        }
}

// ---------------- k_soft (R14): per-bi softmax + agg + fl3 ----------------
// = old k_attn minus the GEMM middle: verbatim rel prologue (cheap recompute,
// REL needed for v_ij), sim loaded straight into the acc2 register layout,
// verbatim softmax/agg/fl3 tail. LDS 17.5KB -> high occupancy.
__global__ __launch_bounds__(256, 3) void k_soft(
    const float* __restrict__ qkv, const float* __restrict__ posb,
    const ushort* __restrict__ pW2b,
    const float* __restrict__ pW1, const float* __restrict__ pb1,
    const float* __restrict__ pb2, const _Float16* __restrict__ sim,
    const float* __restrict__ fl3W, const float* __restrict__ fl3b,
    float* __restrict__ out, long mbase) {
    __shared__ __align__(16) char smem[17472];
    int cpx = gridDim.x >> 3;
    int biL = (blockIdx.x & 7) * cpx + (blockIdx.x >> 3);
    int bL = biL / 50;
    int t = threadIdx.x, w = t >> 6, lane = t & 63;
    int lo16 = lane & 15, hi4 = lane >> 4;

    // ---- phase 0a: h1 fragments in registers (row-split, wave-private) ----
    bf16x8 h_a[2];
    {
        const int jrow = w * 16 + lo16;
        const bool jvalid = jrow < 50;
        float pi0 = posb[biL * 3], pi1 = posb[biL * 3 + 1], pi2 = posb[biL * 3 + 2];
        float d0 = 0.f, d1 = 0.f, d2 = 0.f;
        if (jvalid) {
            int pj = (bL * 50 + jrow) * 3;
            d0 = pi0 - posb[pj]; d1 = pi1 - posb[pj + 1]; d2 = pi2 - posb[pj + 2];
        }
        #pragma unroll
        for (int kt = 0; kt < 2; ++kt) {
            float hv[8];
            #pragma unroll
            for (int e = 0; e < 8; ++e) {
                int ke = kt * 32 + hi4 * 8 + e;
                hv[e] = jvalid
                    ? fmaxf(pb1[ke] + pW1[ke * 3] * d0 + pW1[ke * 3 + 1] * d1
                            + pW1[ke * 3 + 2] * d2, 0.f)
                    : 0.f;
            }
            unsigned* hu = (unsigned*)&h_a[kt];
            #pragma unroll
            for (int i = 0; i < 4; ++i) hu[i] = f2b2(hv[2 * i], hv[2 * i + 1]);
        }
    }

    // ---- phase 0b: rel rows for own 16 j (MFMA K=64) -> REL @0 ----
    {
        f32x4 racc[8];
        #pragma unroll
        for (int n = 0; n < 8; ++n) racc[n] = f32x4{0.f, 0.f, 0.f, 0.f};
        #pragma unroll
        for (int kt = 0; kt < 2; ++kt) {
            int k0 = kt * 32 + hi4 * 8;
            #pragma unroll
            for (int n = 0; n < 8; ++n) {
                bf16x8 bv = *(const bf16x8*)&pW2b[(n * 16 + lo16) * 64 + k0];
                racc[n] = __builtin_amdgcn_mfma_f32_16x16x32_bf16(h_a[kt], bv, racc[n], 0, 0, 0);
            }
        }
        int j0 = w * 16 + hi4 * 4;
        #pragma unroll
        for (int n = 0; n < 8; ++n) {
            int col = n * 16 + lo16;
            float pb = pb2[col];
            unsigned p01 = f2b2(racc[n][0] + pb, racc[n][1] + pb);
            unsigned p23 = f2b2(racc[n][2] + pb, racc[n][3] + pb);
            *(ushort*)(smem + (j0 + 0) * 256 + ((col * 2) ^ (((j0 + 0) & 15) << 4))) = (ushort)p01;
            *(ushort*)(smem + (j0 + 1) * 256 + ((col * 2) ^ (((j0 + 1) & 15) << 4))) = (ushort)(p01 >> 16);
            *(ushort*)(smem + (j0 + 2) * 256 + ((col * 2) ^ (((j0 + 2) & 15) << 4))) = (ushort)p23;
            *(ushort*)(smem + (j0 + 3) * 256 + ((col * 2) ^ (((j0 + 3) & 15) << 4))) = (ushort)(p23 >> 16);
        }
    }
    __syncthreads();   // REL complete (agg reads rows written by other waves)

    // ---- load sim into acc2 layout ----
    f32x4 acc2[4][2];
    #pragma unroll
    for (int m = 0; m < 4; ++m)
        #pragma unroll
        for (int n = 0; n < 2; ++n) {
            int col = w * 32 + n * 16 + lo16;
            #pragma unroll
            for (int rr = 0; rr < 4; ++rr) {
                int j = m * 16 + hi4 * 4 + rr;
                acc2[m][n][rr] = (j < 50)
                    ? (float)sim[(long)(biL * 50 + j) * 128 + col] : 0.f;
            }
        }

    // ---- softmax over j + agg (v_ij = v + rel, rel from REL @0) ----
    float outv[2];
    #pragma unroll
    for (int n = 0; n < 2; ++n) {
        float mx = -1e30f;
        #pragma unroll
        for (int m = 0; m < 4; ++m)
            #pragma unroll
            for (int rr = 0; rr < 4; ++rr) {
                int j = m * 16 + hi4 * 4 + rr;
                if (j < 50) mx = fmaxf(mx, acc2[m][n][rr]);
            }
        mx = fmaxf(mx, __shfl_xor(mx, 16, 64));
        mx = fmaxf(mx, __shfl_xor(mx, 32, 64));
        float e[4][4];
        float sum = 0.f;
        #pragma unroll
        for (int m = 0; m < 4; ++m)
            #pragma unroll
            for (int rr = 0; rr < 4; ++rr) {
                int j = m * 16 + hi4 * 4 + rr;
                float ev = (j < 50) ? __expf(acc2[m][n][rr] - mx) : 0.f;
                e[m][rr] = ev; sum += ev;
            }
        sum += __shfl_xor(sum, 16, 64);
        sum += __shfl_xor(sum, 32, 64);
        float inv = 1.f / sum;
        int col = w * 32 + n * 16 + lo16;
        float ag = 0.f;
        #pragma unroll
        for (int m = 0; m < 4; ++m)
            #pragma unroll
            for (int rr = 0; rr < 4; ++rr) {
                int j = m * 16 + hi4 * 4 + rr;
                if (j < 50) {
                    float rl = b2f(*(const ushort*)(smem + j * 256 +
                                  ((col * 2) ^ ((j & 15) << 4))));
                    float vv = qkv[(long)(bL * 50 + j) * 384 + 256 + col] + rl;
                    ag += e[m][rr] * inv * vv;
                }
            }
        ag += __shfl_xor(ag, 16, 64);
        ag += __shfl_xor(ag, 32, 64);
        outv[n] = ag;
    }
    float* aggF = (float*)(smem + 16384);
    float* part = (float*)(smem + 16896);   // f32[4][36]
    if (hi4 == 0) {
        aggF[w * 32 + lo16] = outv[0];
        aggF[w * 32 + 16 + lo16] = outv[1];
    }
    // fl3 partials: wave-local read of OWN aggF slice (same-wave DS ordering)
    if (lane < 36) {
        const float* wf = &fl3W[lane * 128 + w * 32];
        const float* af = aggF + w * 32;
        float s = 0.f;
        #pragma unroll 8
        for (int d = 0; d < 32; ++d) s += af[d] * wf[d];
        part[w * 36 + lane] = s;
    }
    __syncthreads();

    if (t < 36) {
        float s = fl3b[t] + part[t] + part[36 + t] + part[72 + t] + part[108 + t];
        out[(mbase + biL) * 36 + t] = tanhf(s);
    }
}

// ---------------- launch ----------------
struct Bufs {
    float *sk, *aux, *qkvF, *posb, *WcF, *bc;
    ushort *xh, *actAh, *actBh;
    ushort *l0Wh, *resWh, *Wch, *aW1b, *aW2b, *pW2b;
    ushort *sim;   // _Float16 storage
};

static size_t plan_ws(char* ws, long MCr, Bufs& B) {
    size_t off = 0;
    auto alloc = [&](size_t n) { char* p = ws + off; off += (n + 255) & ~(size_t)255; return p; };
    B.sk    = (float*) alloc(12800L * 4);
    B.aux   = (float*) alloc(128000L * 4);
    B.xh    = (ushort*)alloc((size_t)MCr * 288 * 2);
    B.actAh = (ushort*)alloc((size_t)MCr * 1024 * 2);
    B.actBh = (ushort*)alloc((size_t)MCr * 1024 * 2);
    B.qkvF  = (float*) alloc((size_t)MCr * 384 * 4);
    B.posb  = (float*) alloc((size_t)MCr * 3 * 4);
    B.sim   = (ushort*)alloc((size_t)MCr * 50 * 128 * 2);
    B.l0Wh  = (ushort*)alloc(1024L * 288 * 2);
    B.resWh = (ushort*)alloc(6144L * 1024 * 2);
    B.WcF   = (float*) alloc(384L * 1024 * 4);
    B.Wch   = (ushort*)alloc(384L * 1024 * 2);
    B.bc    = (float*) alloc(384L * 4);
    B.aW1b  = (ushort*)alloc(512L * 128 * 2);
    B.aW2b  = (ushort*)alloc(128L * 512 * 2);
    B.pW2b  = (ushort*)alloc(128L * 64 * 2);
    return off;
}

extern "C" void kernel_launch(void* const* d_in, const int* in_sizes, int n_in,
                              void* d_out, int out_size, void* d_ws, size_t ws_size,
                              hipStream_t stream) {
    (void)in_sizes; (void)n_in;
    const float* input  = (const float*)d_in[0];
    const float* fskel  = (const float*)d_in[1];
    const float* noise  = (const float*)d_in[2];
    const float* firstW = (const float*)d_in[3];
    const float* firstB = (const float*)d_in[4];
    const float* gWih   = (const float*)d_in[5];
    const float* gWhh   = (const float*)d_in[6];
    const float* gbih   = (const float*)d_in[7];
    const float* gbhh   = (const float*)d_in[8];
    const float* l0W    = (const float*)d_in[9];
    const float* l0b    = (const float*)d_in[10];
    const float* resW   = (const float*)d_in[11];
    const float* resB   = (const float*)d_in[12];
    const float* bnG    = (const float*)d_in[13];
    const float* bnB    = (const float*)d_in[14];
    const float* bnM    = (const float*)d_in[15];
    const float* bnV    = (const float*)d_in[16];
    const float* fl1W   = (const float*)d_in[17];
    const float* fl1b   = (const float*)d_in[18];
    const float* fl2W   = (const float*)d_in[19];
    const float* fl2b   = (const float*)d_in[20];
    const float* fl3W   = (const float*)d_in[21];
    const float* fl3b   = (const float*)d_in[22];
    const float* qkvW   = (const float*)d_in[23];
    const float* pW1    = (const float*)d_in[24];
    const float* pb1    = (const float*)d_in[25];
    const float* pW2    = (const float*)d_in[26];
    const float* pb2    = (const float*)d_in[27];
    const float* aW1    = (const float*)d_in[28];
    const float* ab1    = (const float*)d_in[29];
    const float* aW2    = (const float*)d_in[30];
    float* out = (float*)d_out;

    char* ws = (char*)d_ws;
    Bufs B;
    long MCr = 12800;
    while (plan_ws(ws, MCr, B) > ws_size) {
        MCr >>= 1;                                 // 6400, 3200, 1600 (all %50==0)
        if (MCr < 1600) {                          // diagnostic: clean zero output
            hipMemsetAsync(d_out, 0, (size_t)out_size * sizeof(float), stream);
            return;
        }
    }
    const int nchunks = (int)(12800 / MCr);

    // one-time prep
    k_split<<<1152, 256, 0, stream>>>(l0W, B.l0Wh, nullptr, 1024, 267, 288);
    k_split<<<8192, 256, 0, stream>>>(resW, B.resWh, nullptr, 6144, 1024, 1024);
    k_wc<<<1536, 256, 0, stream>>>(qkvW, fl1W, fl1b, B.WcF, B.bc);
    k_split<<<1536, 256, 0, stream>>>(B.WcF, B.Wch, nullptr, 384, 1024, 1024);
    k_split<<<256, 256, 0, stream>>>(aW1, B.aW1b, nullptr, 512, 128, 128);
    k_split<<<256, 256, 0, stream>>>(aW2, B.aW2b, nullptr, 128, 512, 512);
    k_split<<<32, 256, 0, stream>>>(pW2, B.pW2b, nullptr, 128, 64, 64);
    k_sk<<<50, 256, 0, stream>>>(fskel, firstW, firstB, B.sk);
    k_gru<<<256, 64, 0, stream>>>(noise, gWih, gWhh, gbih, gbhh, B.aux);

    for (int c = 0; c < nchunks; ++c) {
        long mbase = (long)c * MCr;
        int xb_grid = (int)((MCr * 288 + 255) / 256);
        k_xbuild<<<xb_grid, 256, 0, stream>>>(input + mbase * 256, B.aux + mbase * 10,
                                              B.sk + mbase, B.xh, MCr);
        dim3 gt(8, (unsigned)(MCr / 128));
        k_gemm<0><<<gt, 256, 0, stream>>>(B.xh, B.l0Wh, 1024, 288,
            nullptr, B.actAh, l0b, nullptr, nullptr, nullptr, nullptr, nullptr);
        for (int blk = 0; blk < 3; ++blk) {
            int j0 = blk * 2, j1 = blk * 2 + 1;
            k_gemm<1><<<gt, 256, 0, stream>>>(B.actAh,
                B.resWh + (size_t)j0 * 1024 * 1024,
                1024, 1024, nullptr, B.actBh, resB + j0 * 1024,
                bnG + j0 * 1024, bnB + j0 * 1024, bnM + j0 * 1024, bnV + j0 * 1024,
                nullptr);
            k_gemm<2><<<gt, 256, 0, stream>>>(B.actBh,
                B.resWh + (size_t)j1 * 1024 * 1024,
                1024, 1024, nullptr, B.actAh, resB + j1 * 1024,
                bnG + j1 * 1024, bnB + j1 * 1024, bnM + j1 * 1024, bnV + j1 * 1024,
                B.actAh);
        }
        dim3 gq(3, (unsigned)(MCr / 128));
        k_gemm<0><<<gq, 256, 0, stream>>>(B.actAh, B.Wch, 384, 1024,
            B.qkvF, nullptr, B.bc, nullptr, nullptr, nullptr, nullptr, nullptr);
        k_fl2<<<(int)(MCr / 4), 256, 0, stream>>>(B.actAh, fl2W, fl2b, B.posb);
        int nsim = (int)(MCr * 50 / 128);
        k_sim<<<nsim, 256, 0, stream>>>(B.qkvF, B.posb, B.aW1b, B.aW2b, ab1, B.pW2b,
                                        pW1, pb1, pb2, (_Float16*)B.sim);
        k_soft<<<(int)MCr, 256, 0, stream>>>(B.qkvF, B.posb, B.pW2b, pW1, pb1, pb2,
                                             (const _Float16*)B.sim, fl3W, fl3b,
                                             out, mbase);
    }
}